// Round 1
// baseline (437.712 us; speedup 1.0000x reference)
//
#include <hip/hip_runtime.h>

#define Bb 2
#define Tt 2048
#define Mm 2048
#define Hh 16
#define Dd 128

typedef __attribute__((ext_vector_type(8))) short bf16x8;
typedef __attribute__((ext_vector_type(4))) float f32x4;

__device__ __forceinline__ unsigned short f2bf(float f) {
    unsigned int u = __builtin_bit_cast(unsigned int, f);
    u += 0x7FFFu + ((u >> 16) & 1u);   // RNE
    return (unsigned short)(u >> 16);
}

__device__ __forceinline__ float fexp2(float x) { return __builtin_amdgcn_exp2f(x); }

// ---------------------------------------------------------------- prep kernels

__global__ __launch_bounds__(256) void cvt_x_kernel(const float* __restrict__ x,
                                                    unsigned short* __restrict__ xb) {
    long i = ((long)blockIdx.x * 256 + threadIdx.x) * 4;
    float4 v = *(const float4*)(x + i);
    unsigned short r0 = f2bf(v.x), r1 = f2bf(v.y), r2 = f2bf(v.z), r3 = f2bf(v.w);
    unsigned int lo = (unsigned int)r0 | ((unsigned int)r1 << 16);
    unsigned int hi = (unsigned int)r2 | ((unsigned int)r3 << 16);
    uint2 packed; packed.x = lo; packed.y = hi;
    *(uint2*)(xb + i) = packed;
}

// in: rows x cols row-major fp32 (slab blockIdx.z), out: cols x rows bf16
__global__ __launch_bounds__(256) void transpose_cvt(const float* __restrict__ in,
                                                     unsigned short* __restrict__ out,
                                                     int rows, int cols,
                                                     long in_slab, long out_slab) {
    __shared__ float tile[32][33];
    const float* ip = in + (long)blockIdx.z * in_slab;
    unsigned short* op = out + (long)blockIdx.z * out_slab;
    int r0 = blockIdx.x * 32, c0 = blockIdx.y * 32;
    int tx = threadIdx.x & 31, ty = threadIdx.x >> 5;  // ty 0..7
#pragma unroll
    for (int j = 0; j < 32; j += 8)
        tile[ty + j][tx] = ip[(long)(r0 + ty + j) * cols + c0 + tx];
    __syncthreads();
#pragma unroll
    for (int j = 0; j < 32; j += 8)
        op[(long)(c0 + ty + j) * rows + r0 + tx] = f2bf(tile[tx][ty + j]);
}

__global__ __launch_bounds__(256) void rope_tab(float* __restrict__ cosT,
                                                float* __restrict__ sinT) {
    int idx = blockIdx.x * 256 + threadIdx.x;   // T*64 = 131072
    int t = idx >> 6, d = idx & 63;
    float freq = powf(10000.f, -(float)d / 64.f);
    float ang = (float)t * freq;
    sinT[idx] = sinf(ang);
    cosT[idx] = cosf(ang);
}

// ---------------------------------------------------------------- QKV projection GEMM
// A = xb (4096 x 2048) bf16 row-major, B^T = wT (2048 x 2048) bf16 (n-major, k-contig)
// mode 0: q (rope, out (B,H,T,D)); mode 1: k (rope); mode 2: v (out transposed (B,H,D,T))
__global__ __launch_bounds__(256) void proj_gemm(
    const unsigned short* __restrict__ xb,
    const unsigned short* __restrict__ wqT,
    const unsigned short* __restrict__ wkT,
    const unsigned short* __restrict__ wvT,
    unsigned short* __restrict__ qO,
    unsigned short* __restrict__ kO,
    unsigned short* __restrict__ vtO,
    const float* __restrict__ cosT,
    const float* __restrict__ sinT) {
    __shared__ __align__(16) unsigned short smem[16384];   // 32 KB
    unsigned short* As = smem;          // [128][64]
    unsigned short* Bs = smem + 8192;   // [128][64] (n x k)

    const int mode = blockIdx.z;
    const unsigned short* wT = (mode == 0) ? wqT : (mode == 1) ? wkT : wvT;
    const int bm = blockIdx.x;   // 0..31 row tile
    const int h  = blockIdx.y;   // 0..15 head (= 128-col tile)
    const int tid = threadIdx.x;
    const int lane = tid & 63;
    const int wave = tid >> 6;
    const int g = lane >> 4;
    const int ln = lane & 15;

    const unsigned short* arow = xb + (long)bm * 128 * Mm;
    const unsigned short* brow = wT + (long)h * 128 * Mm;

    f32x4 acc[2][8];
#pragma unroll
    for (int a = 0; a < 2; ++a)
#pragma unroll
        for (int b2 = 0; b2 < 8; ++b2)
#pragma unroll
            for (int e = 0; e < 4; ++e) acc[a][b2][e] = 0.f;

    for (int kt = 0; kt < Mm / 64; ++kt) {
        const int k0 = kt * 64;
        __syncthreads();
#pragma unroll
        for (int it = 0; it < 4; ++it) {
            int f = it * 256 + tid;         // 0..1023
            int r = f >> 3, c8 = f & 7;
            uint4 da = *(const uint4*)(arow + (long)r * Mm + k0 + c8 * 8);
            uint4 db = *(const uint4*)(brow + (long)r * Mm + k0 + c8 * 8);
            int byte = (r * 128 + c8 * 16) ^ ((r & 7) << 4);
            *(uint4*)((char*)As + byte) = da;
            *(uint4*)((char*)Bs + byte) = db;
        }
        __syncthreads();
#pragma unroll
        for (int kc = 0; kc < 2; ++kc) {
            bf16x8 af[2];
#pragma unroll
            for (int rf = 0; rf < 2; ++rf) {
                int row = wave * 32 + rf * 16 + ln;
                int byte = (row * 128 + kc * 64 + g * 16) ^ ((row & 7) << 4);
                af[rf] = *(const bf16x8*)((char*)As + byte);
            }
#pragma unroll
            for (int ni = 0; ni < 8; ++ni) {
                int row = ni * 16 + ln;
                int byte = (row * 128 + kc * 64 + g * 16) ^ ((row & 7) << 4);
                bf16x8 bfv = *(const bf16x8*)((char*)Bs + byte);
#pragma unroll
                for (int rf = 0; rf < 2; ++rf)
                    acc[rf][ni] = __builtin_amdgcn_mfma_f32_16x16x32_bf16(af[rf], bfv, acc[rf][ni], 0, 0, 0);
            }
        }
    }

    const int b  = bm >> 4;
    const int t0 = (bm & 15) * 128;

    if (mode < 2) {
        unsigned short* out = (mode == 0) ? qO : kO;
        long hb = ((long)(b * Hh + h)) * Tt;
#pragma unroll
        for (int rf = 0; rf < 2; ++rf)
#pragma unroll
            for (int reg = 0; reg < 4; ++reg) {
                int i = wave * 32 + rf * 16 + g * 4 + reg;
                int t = t0 + i;
                long base = (hb + t) * Dd;
#pragma unroll
                for (int ni = 0; ni < 4; ++ni) {
                    int d = ni * 16 + ln;
                    float c = cosT[t * 64 + d];
                    float s = sinT[t * 64 + d];
                    float ev = acc[rf][ni][reg];
                    float od = acc[rf][ni + 4][reg];
                    out[base + d]      = f2bf(ev * c - od * s);
                    out[base + d + 64] = f2bf(ev * s + od * c);
                }
            }
    } else {
        // transpose epilogue: vt[b][h][d][t]
        __syncthreads();   // all waves done reading As/Bs
        // Ls = smem as [128 d][128 t] bf16, byte = d*256 + i*2, swizzled
#pragma unroll
        for (int rf = 0; rf < 2; ++rf)
#pragma unroll
            for (int ni = 0; ni < 8; ++ni)
#pragma unroll
                for (int reg = 0; reg < 4; ++reg) {
                    int i = wave * 32 + rf * 16 + g * 4 + reg;
                    int d = ni * 16 + ln;
                    int byte = (d * 256 + i * 2) ^ ((d & 7) << 4);
                    *(unsigned short*)((char*)smem + byte) = f2bf(acc[rf][ni][reg]);
                }
        __syncthreads();
        long hb = ((long)(b * Hh + h)) * Dd;
#pragma unroll
        for (int rep = 0; rep < 8; ++rep) {
            int d = rep * 16 + (tid >> 4);
            int tb = tid & 15;
            int byte = (d * 256 + tb * 16) ^ ((d & 7) << 4);
            uint4 v = *(const uint4*)((char*)smem + byte);
            *(uint4*)(vtO + ((hb + d) * Tt + t0 + tb * 8)) = v;
        }
    }
}

// ---------------------------------------------------------------- flash attention
// q,k: (B,H,T,D) bf16 roped; vt: (B,H,D,T) bf16; o: (B,T,H,D) bf16
__global__ __launch_bounds__(256) void attn_kernel(
    const unsigned short* __restrict__ q,
    const unsigned short* __restrict__ k,
    const unsigned short* __restrict__ vt,
    unsigned short* __restrict__ o) {
    __shared__ __align__(16) unsigned short Ks[8192];     // [64 j][128 d]
    __shared__ __align__(16) unsigned short Vts[8192];    // [128 d][64 j]
    __shared__ __align__(16) unsigned short Ps[4][2048];  // per wave [32 i][64 j]

    const int qb = (int)(gridDim.x - 1 - blockIdx.x);   // big blocks first
    const int bh = blockIdx.y;
    const int tid = threadIdx.x, lane = tid & 63, wave = tid >> 6;
    const int g = lane >> 4, ln = lane & 15;

    const unsigned short* qp = q + (long)bh * Tt * Dd;
    const unsigned short* kp = k + (long)bh * Tt * Dd;
    const unsigned short* vp = vt + (long)bh * Dd * Tt;

    // Q fragments in registers (rows = qb*128 + wave*32 + rf*16 + ln)
    bf16x8 qf[2][4];
#pragma unroll
    for (int rf = 0; rf < 2; ++rf) {
        int t = qb * 128 + wave * 32 + rf * 16 + ln;
#pragma unroll
        for (int kc = 0; kc < 4; ++kc)
            qf[rf][kc] = *(const bf16x8*)(qp + (long)t * Dd + kc * 32 + g * 8);
    }

    f32x4 accO[2][8];
#pragma unroll
    for (int a = 0; a < 2; ++a)
#pragma unroll
        for (int b2 = 0; b2 < 8; ++b2)
#pragma unroll
            for (int e = 0; e < 4; ++e) accO[a][b2][e] = 0.f;

    float m_r[2][4], l_r[2][4];
#pragma unroll
    for (int a = 0; a < 2; ++a)
#pragma unroll
        for (int r = 0; r < 4; ++r) { m_r[a][r] = -1e30f; l_r[a][r] = 0.f; }

    const int ntiles = 2 * qb + 2;
    const float SC = 0.011271055007f;   // log2(e)/128  (mult^2 = 1/D folded with exp2)

    for (int tix = 0; tix < ntiles; ++tix) {
        const int j0 = tix * 64;
        __syncthreads();
#pragma unroll
        for (int it = 0; it < 4; ++it) {
            int f = it * 256 + tid;
            {
                int r = f >> 4, c8 = f & 15;
                uint4 dk = *(const uint4*)(kp + (long)(j0 + r) * Dd + c8 * 8);
                int byte = (r * 256 + c8 * 16) ^ ((r & 7) << 4);
                *(uint4*)((char*)Ks + byte) = dk;
            }
            {
                int r = f >> 3, c8 = f & 7;
                uint4 dv = *(const uint4*)(vp + (long)r * Tt + j0 + c8 * 8);
                int byte = (r * 128 + c8 * 16) ^ ((r & 7) << 4);
                *(uint4*)((char*)Vts + byte) = dv;
            }
        }
        __syncthreads();

        // S = Q K^T  (sa[rf][ni], C-layout: row=(g*4+reg), col=ln)
        f32x4 sa[2][4];
#pragma unroll
        for (int a = 0; a < 2; ++a)
#pragma unroll
            for (int b2 = 0; b2 < 4; ++b2)
#pragma unroll
                for (int e = 0; e < 4; ++e) sa[a][b2][e] = 0.f;
#pragma unroll
        for (int ni = 0; ni < 4; ++ni) {
            bf16x8 kf[4];
#pragma unroll
            for (int kc = 0; kc < 4; ++kc) {
                int row = ni * 16 + ln;
                int byte = (row * 256 + kc * 64 + g * 16) ^ ((row & 7) << 4);
                kf[kc] = *(const bf16x8*)((char*)Ks + byte);
            }
#pragma unroll
            for (int rf = 0; rf < 2; ++rf)
#pragma unroll
                for (int kc = 0; kc < 4; ++kc)
                    sa[rf][ni] = __builtin_amdgcn_mfma_f32_16x16x32_bf16(qf[rf][kc], kf[kc], sa[rf][ni], 0, 0, 0);
        }

        // scale + causal mask (only last two tiles can be masked)
        const bool domask = (j0 + 63 > qb * 128);
#pragma unroll
        for (int rf = 0; rf < 2; ++rf)
#pragma unroll
            for (int ni = 0; ni < 4; ++ni)
#pragma unroll
                for (int reg = 0; reg < 4; ++reg) {
                    float v = sa[rf][ni][reg] * SC;
                    if (domask) {
                        int i = qb * 128 + wave * 32 + rf * 16 + g * 4 + reg;
                        int j = j0 + ni * 16 + ln;
                        if (j > i) v = -1e30f;
                    }
                    sa[rf][ni][reg] = v;
                }

        // online softmax update
#pragma unroll
        for (int rf = 0; rf < 2; ++rf)
#pragma unroll
            for (int reg = 0; reg < 4; ++reg) {
                float mx = fmaxf(fmaxf(sa[rf][0][reg], sa[rf][1][reg]),
                                 fmaxf(sa[rf][2][reg], sa[rf][3][reg]));
                mx = fmaxf(mx, __shfl_xor(mx, 1, 64));
                mx = fmaxf(mx, __shfl_xor(mx, 2, 64));
                mx = fmaxf(mx, __shfl_xor(mx, 4, 64));
                mx = fmaxf(mx, __shfl_xor(mx, 8, 64));
                float mo = m_r[rf][reg];
                float mn = fmaxf(mo, mx);
                float corr = fexp2(mo - mn);
                m_r[rf][reg] = mn;
                l_r[rf][reg] *= corr;
#pragma unroll
                for (int ni = 0; ni < 8; ++ni) accO[rf][ni][reg] *= corr;

                float rs = 0.f;
#pragma unroll
                for (int ni = 0; ni < 4; ++ni) {
                    float p = fexp2(sa[rf][ni][reg] - mn);
                    sa[rf][ni][reg] = p;
                    rs += p;
                }
                rs += __shfl_xor(rs, 1, 64);
                rs += __shfl_xor(rs, 2, 64);
                rs += __shfl_xor(rs, 4, 64);
                rs += __shfl_xor(rs, 8, 64);
                l_r[rf][reg] += rs;
            }

        // P -> LDS (bf16), per-wave region, swizzled [32][64]
        unsigned short* Pw = Ps[wave];
#pragma unroll
        for (int rf = 0; rf < 2; ++rf)
#pragma unroll
            for (int ni = 0; ni < 4; ++ni)
#pragma unroll
                for (int reg = 0; reg < 4; ++reg) {
                    int i = rf * 16 + g * 4 + reg;
                    int j = ni * 16 + ln;
                    int byte = (i * 128 + j * 2) ^ ((i & 7) << 4);
                    *(unsigned short*)((char*)Pw + byte) = f2bf(sa[rf][ni][reg]);
                }
        __syncthreads();

        // O += P V   (A-op = P rows i, B-op = Vt rows d)
        bf16x8 pf[2][2];
#pragma unroll
        for (int rf = 0; rf < 2; ++rf)
#pragma unroll
            for (int jc = 0; jc < 2; ++jc) {
                int i = rf * 16 + ln;
                int byte = (i * 128 + jc * 64 + g * 16) ^ ((i & 7) << 4);
                pf[rf][jc] = *(const bf16x8*)((char*)Pw + byte);
            }
#pragma unroll
        for (int ni = 0; ni < 8; ++ni)
#pragma unroll
            for (int jc = 0; jc < 2; ++jc) {
                int row = ni * 16 + ln;
                int byte = (row * 128 + jc * 64 + g * 16) ^ ((row & 7) << 4);
                bf16x8 vf = *(const bf16x8*)((char*)Vts + byte);
#pragma unroll
                for (int rf = 0; rf < 2; ++rf)
                    accO[rf][ni] = __builtin_amdgcn_mfma_f32_16x16x32_bf16(pf[rf][jc], vf, accO[rf][ni], 0, 0, 0);
            }
    }

    // epilogue: o[b][t][h][d] = accO / l
    const int b = bh >> 4, hh = bh & 15;
#pragma unroll
    for (int rf = 0; rf < 2; ++rf)
#pragma unroll
        for (int reg = 0; reg < 4; ++reg) {
            float inv = 1.f / l_r[rf][reg];
            int t = qb * 128 + wave * 32 + rf * 16 + g * 4 + reg;
            long base = ((long)(b * Tt + t) * Hh + hh) * Dd;
#pragma unroll
            for (int ni = 0; ni < 8; ++ni) {
                int d = ni * 16 + ln;
                o[base + d] = f2bf(accO[rf][ni][reg] * inv);
            }
        }
}

// ---------------------------------------------------------------- output projection GEMM
__global__ __launch_bounds__(256) void out_gemm(
    const unsigned short* __restrict__ oIn,
    const unsigned short* __restrict__ woT,
    float* __restrict__ out) {
    __shared__ __align__(16) unsigned short smem[16384];
    unsigned short* As = smem;
    unsigned short* Bs = smem + 8192;
    const int bm = blockIdx.x, bn = blockIdx.y;
    const int tid = threadIdx.x;
    const int lane = tid & 63;
    const int wave = tid >> 6;
    const int g = lane >> 4;
    const int ln = lane & 15;

    const unsigned short* arow = oIn + (long)bm * 128 * Mm;
    const unsigned short* brow = woT + (long)bn * 128 * Mm;

    f32x4 acc[2][8];
#pragma unroll
    for (int a = 0; a < 2; ++a)
#pragma unroll
        for (int b2 = 0; b2 < 8; ++b2)
#pragma unroll
            for (int e = 0; e < 4; ++e) acc[a][b2][e] = 0.f;

    for (int kt = 0; kt < Mm / 64; ++kt) {
        const int k0 = kt * 64;
        __syncthreads();
#pragma unroll
        for (int it = 0; it < 4; ++it) {
            int f = it * 256 + tid;
            int r = f >> 3, c8 = f & 7;
            uint4 da = *(const uint4*)(arow + (long)r * Mm + k0 + c8 * 8);
            uint4 db = *(const uint4*)(brow + (long)r * Mm + k0 + c8 * 8);
            int byte = (r * 128 + c8 * 16) ^ ((r & 7) << 4);
            *(uint4*)((char*)As + byte) = da;
            *(uint4*)((char*)Bs + byte) = db;
        }
        __syncthreads();
#pragma unroll
        for (int kc = 0; kc < 2; ++kc) {
            bf16x8 af[2];
#pragma unroll
            for (int rf = 0; rf < 2; ++rf) {
                int row = wave * 32 + rf * 16 + ln;
                int byte = (row * 128 + kc * 64 + g * 16) ^ ((row & 7) << 4);
                af[rf] = *(const bf16x8*)((char*)As + byte);
            }
#pragma unroll
            for (int ni = 0; ni < 8; ++ni) {
                int row = ni * 16 + ln;
                int byte = (row * 128 + kc * 64 + g * 16) ^ ((row & 7) << 4);
                bf16x8 bfv = *(const bf16x8*)((char*)Bs + byte);
#pragma unroll
                for (int rf = 0; rf < 2; ++rf)
                    acc[rf][ni] = __builtin_amdgcn_mfma_f32_16x16x32_bf16(af[rf], bfv, acc[rf][ni], 0, 0, 0);
            }
        }
    }

#pragma unroll
    for (int rf = 0; rf < 2; ++rf)
#pragma unroll
        for (int reg = 0; reg < 4; ++reg) {
            long row = bm * 128 + wave * 32 + rf * 16 + g * 4 + reg;
#pragma unroll
            for (int ni = 0; ni < 8; ++ni)
                out[row * Mm + bn * 128 + ni * 16 + ln] = acc[rf][ni][reg];
        }
}

// ---------------------------------------------------------------- launch

extern "C" void kernel_launch(void* const* d_in, const int* in_sizes, int n_in,
                              void* d_out, int out_size, void* d_ws, size_t ws_size,
                              hipStream_t stream) {
    const float* x    = (const float*)d_in[0];
    const float* w_aq = (const float*)d_in[1];
    const float* w_ak = (const float*)d_in[2];
    const float* w_av = (const float*)d_in[3];
    const float* w_ao = (const float*)d_in[4];
    float* out = (float*)d_out;

    char* ws = (char*)d_ws;
    const long SZ_BTM = 16777216;   // B*T*M * 2B (also B*H*T*D * 2B)
    const long SZ_W   = 8388608;    // 2048*2048 * 2B
    unsigned short* xb  = (unsigned short*)(ws);
    unsigned short* qB  = (unsigned short*)(ws + SZ_BTM);
    unsigned short* kB  = (unsigned short*)(ws + 2 * SZ_BTM);
    unsigned short* vtB = (unsigned short*)(ws + 3 * SZ_BTM);
    unsigned short* oB  = (unsigned short*)(ws + 4 * SZ_BTM);
    unsigned short* wqT = (unsigned short*)(ws + 5 * SZ_BTM);
    unsigned short* wkT = (unsigned short*)(ws + 5 * SZ_BTM + SZ_W);
    unsigned short* wvT = (unsigned short*)(ws + 5 * SZ_BTM + 2 * SZ_W);
    unsigned short* woT = (unsigned short*)(ws + 5 * SZ_BTM + 3 * SZ_W);
    float* cosT = (float*)(ws + 5 * SZ_BTM + 4 * SZ_W);
    float* sinT = (float*)(ws + 5 * SZ_BTM + 4 * SZ_W + 524288);

    cvt_x_kernel<<<8192, 256, 0, stream>>>(x, xb);
    transpose_cvt<<<dim3(64, 4, 16), 256, 0, stream>>>(w_aq, wqT, 2048, 128, (long)2048 * 128, (long)128 * 2048);
    transpose_cvt<<<dim3(64, 4, 16), 256, 0, stream>>>(w_ak, wkT, 2048, 128, (long)2048 * 128, (long)128 * 2048);
    transpose_cvt<<<dim3(64, 4, 16), 256, 0, stream>>>(w_av, wvT, 2048, 128, (long)2048 * 128, (long)128 * 2048);
    transpose_cvt<<<dim3(64, 64, 1), 256, 0, stream>>>(w_ao, woT, 2048, 2048, 0, 0);
    rope_tab<<<512, 256, 0, stream>>>(cosT, sinT);

    proj_gemm<<<dim3(32, 16, 3), 256, 0, stream>>>(xb, wqT, wkT, wvT, qB, kB, vtB, cosT, sinT);
    attn_kernel<<<dim3(16, 32), 256, 0, stream>>>(qB, kB, vtB, oB);
    out_gemm<<<dim3(32, 16), 256, 0, stream>>>(oB, woT, out);
}

// Round 2
// 315.372 us; speedup vs baseline: 1.3879x; 1.3879x over previous
//
#include <hip/hip_runtime.h>

#define Bb 2
#define Tt 2048
#define Mm 2048
#define Hh 16
#define Dd 128

typedef __attribute__((ext_vector_type(8))) short bf16x8;
typedef __attribute__((ext_vector_type(4))) float f32x4;

__device__ __forceinline__ unsigned short f2bf(float f) {
    unsigned int u = __builtin_bit_cast(unsigned int, f);
    u += 0x7FFFu + ((u >> 16) & 1u);   // RNE
    return (unsigned short)(u >> 16);
}

__device__ __forceinline__ float fexp2(float x) { return __builtin_amdgcn_exp2f(x); }

__device__ __forceinline__ void gld16(const void* g, void* l) {
    __builtin_amdgcn_global_load_lds(
        (const __attribute__((address_space(1))) void*)g,
        (__attribute__((address_space(3))) void*)l, 16, 0, 0);
}

// ---------------------------------------------------------------- prep kernels

__global__ __launch_bounds__(256) void cvt_x_kernel(const float* __restrict__ x,
                                                    unsigned short* __restrict__ xb) {
    long i = ((long)blockIdx.x * 256 + threadIdx.x) * 4;
    float4 v = *(const float4*)(x + i);
    unsigned short r0 = f2bf(v.x), r1 = f2bf(v.y), r2 = f2bf(v.z), r3 = f2bf(v.w);
    unsigned int lo = (unsigned int)r0 | ((unsigned int)r1 << 16);
    unsigned int hi = (unsigned int)r2 | ((unsigned int)r3 << 16);
    uint2 packed; packed.x = lo; packed.y = hi;
    *(uint2*)(xb + i) = packed;
}

__global__ __launch_bounds__(256) void transpose_cvt(const float* __restrict__ in,
                                                     unsigned short* __restrict__ out,
                                                     int rows, int cols,
                                                     long in_slab, long out_slab) {
    __shared__ float tile[32][33];
    const float* ip = in + (long)blockIdx.z * in_slab;
    unsigned short* op = out + (long)blockIdx.z * out_slab;
    int r0 = blockIdx.x * 32, c0 = blockIdx.y * 32;
    int tx = threadIdx.x & 31, ty = threadIdx.x >> 5;
#pragma unroll
    for (int j = 0; j < 32; j += 8)
        tile[ty + j][tx] = ip[(long)(r0 + ty + j) * cols + c0 + tx];
    __syncthreads();
#pragma unroll
    for (int j = 0; j < 32; j += 8)
        op[(long)(c0 + ty + j) * rows + r0 + tx] = f2bf(tile[tx][ty + j]);
}

__global__ __launch_bounds__(256) void rope_tab(float* __restrict__ cosT,
                                                float* __restrict__ sinT) {
    int idx = blockIdx.x * 256 + threadIdx.x;   // T*64
    int t = idx >> 6, d = idx & 63;
    float freq = powf(10000.f, -(float)d / 64.f);
    float ang = (float)t * freq;
    sinT[idx] = sinf(ang);
    cosT[idx] = cosf(ang);
}

// ---------------------------------------------------------------- QKV projection GEMM
// A = xb (4096 x 2048) bf16 row-major, B^T = wT (2048 x 2048) bf16 (n-major, k-contig)
// mode 0: q (rope + 1/D*log2e scale); mode 1: k (rope); mode 2: v (out transposed (B,H,D,T))
__global__ __launch_bounds__(256) void proj_gemm(
    const unsigned short* __restrict__ xb,
    const unsigned short* __restrict__ wqT,
    const unsigned short* __restrict__ wkT,
    const unsigned short* __restrict__ wvT,
    unsigned short* __restrict__ qO,
    unsigned short* __restrict__ kO,
    unsigned short* __restrict__ vtO,
    const float* __restrict__ cosT,
    const float* __restrict__ sinT) {
    // As0 @0, Bs0 @16384, As1 @32768, Bs1 @49152  (bytes)
    __shared__ __align__(16) unsigned short smem[32768];   // 64 KB

    const int mode = blockIdx.z;
    const unsigned short* wT = (mode == 0) ? wqT : (mode == 1) ? wkT : wvT;
    const int bm = blockIdx.x;
    const int h  = blockIdx.y;
    const int tid = threadIdx.x;
    const int lane = tid & 63;
    const int wave = tid >> 6;
    const int g = lane >> 4;
    const int ln = lane & 15;

    const unsigned short* arow = xb + (long)bm * 128 * Mm;
    const unsigned short* brow = wT + (long)h * 128 * Mm;

    f32x4 acc[2][8];
#pragma unroll
    for (int a = 0; a < 2; ++a)
#pragma unroll
        for (int b2 = 0; b2 < 8; ++b2)
#pragma unroll
            for (int e = 0; e < 4; ++e) acc[a][b2][e] = 0.f;

    auto stage = [&](int buf, int kt) {
        const int k0 = kt * 64;
#pragma unroll
        for (int it = 0; it < 4; ++it) {
            int f = it * 256 + tid;
            int r = f >> 3, c = f & 7;
            long off = (long)r * Mm + k0 + ((c ^ (r & 7)) << 3);
            gld16(arow + off, (char*)smem + buf * 32768 + f * 16);
            gld16(brow + off, (char*)smem + buf * 32768 + 16384 + f * 16);
        }
    };

    stage(0, 0);

    for (int kt = 0; kt < Mm / 64; ++kt) {
        const int cur = kt & 1;
        if (kt + 1 < Mm / 64) {
            stage(cur ^ 1, kt + 1);
            asm volatile("s_waitcnt vmcnt(8)" ::: "memory");
        } else {
            asm volatile("s_waitcnt vmcnt(0)" ::: "memory");
        }
        __builtin_amdgcn_s_barrier();

        const char* Ab = (const char*)smem + cur * 32768;
        const char* Bv = Ab + 16384;
#pragma unroll
        for (int kc = 0; kc < 2; ++kc) {
            bf16x8 af[2];
#pragma unroll
            for (int rf = 0; rf < 2; ++rf) {
                int row = wave * 32 + rf * 16 + ln;
                int byte = (row * 128 + kc * 64 + g * 16) ^ ((row & 7) << 4);
                af[rf] = *(const bf16x8*)(Ab + byte);
            }
#pragma unroll
            for (int ni = 0; ni < 8; ++ni) {
                int row = ni * 16 + ln;
                int byte = (row * 128 + kc * 64 + g * 16) ^ ((row & 7) << 4);
                bf16x8 bfv = *(const bf16x8*)(Bv + byte);
#pragma unroll
                for (int rf = 0; rf < 2; ++rf)
                    acc[rf][ni] = __builtin_amdgcn_mfma_f32_16x16x32_bf16(af[rf], bfv, acc[rf][ni], 0, 0, 0);
            }
        }
        asm volatile("" ::: "memory");
        __builtin_amdgcn_s_barrier();
    }

    const int b  = bm >> 4;
    const int t0 = (bm & 15) * 128;

    if (mode < 2) {
        const float qscale = (mode == 0) ? 0.011271055f : 1.0f;  // log2(e)/D on q only
        unsigned short* out = (mode == 0) ? qO : kO;
        long hb = ((long)(b * Hh + h)) * Tt;
#pragma unroll
        for (int rf = 0; rf < 2; ++rf)
#pragma unroll
            for (int reg = 0; reg < 4; ++reg) {
                int i = wave * 32 + rf * 16 + g * 4 + reg;
                int t = t0 + i;
                long base = (hb + t) * Dd;
#pragma unroll
                for (int ni = 0; ni < 4; ++ni) {
                    int d = ni * 16 + ln;
                    float c = cosT[t * 64 + d];
                    float s = sinT[t * 64 + d];
                    float ev = acc[rf][ni][reg];
                    float od = acc[rf][ni + 4][reg];
                    out[base + d]      = f2bf((ev * c - od * s) * qscale);
                    out[base + d + 64] = f2bf((ev * s + od * c) * qscale);
                }
            }
    } else {
        // transpose epilogue: vt[b][h][d][t]; scratch = first 32KB of smem
        __syncthreads();
#pragma unroll
        for (int rf = 0; rf < 2; ++rf)
#pragma unroll
            for (int ni = 0; ni < 8; ++ni)
#pragma unroll
                for (int reg = 0; reg < 4; ++reg) {
                    int i = wave * 32 + rf * 16 + g * 4 + reg;
                    int d = ni * 16 + ln;
                    int byte = (d * 256 + i * 2) ^ ((d & 7) << 4);
                    *(unsigned short*)((char*)smem + byte) = f2bf(acc[rf][ni][reg]);
                }
        __syncthreads();
        long hb = ((long)(b * Hh + h)) * Dd;
#pragma unroll
        for (int rep = 0; rep < 8; ++rep) {
            int d = rep * 16 + (tid >> 4);
            int tb = tid & 15;
            int byte = (d * 256 + tb * 16) ^ ((d & 7) << 4);
            uint4 v = *(const uint4*)((char*)smem + byte);
            *(uint4*)(vtO + ((hb + d) * Tt + t0 + tb * 8)) = v;
        }
    }
}

// ---------------------------------------------------------------- flash attention
// q (pre-scaled by log2e/D), k: (B,H,T,D) bf16 roped; vt: (B,H,D,T) bf16; o: (B,T,H,D) bf16
__global__ __launch_bounds__(256) void attn_kernel(
    const unsigned short* __restrict__ q,
    const unsigned short* __restrict__ k,
    const unsigned short* __restrict__ vt,
    unsigned short* __restrict__ o) {
    // Ks0 @0, Ks1 @16384, Vt0 @32768, Vt1 @49152, Ps @65536  (bytes), 80KB total
    __shared__ __align__(16) unsigned short lds[40960];

    // pairing remap: blocks n and n+256 get complementary qb -> per-CU work constant
    const int lid = (int)blockIdx.x;
    const int p = lid & 255;
    const int bh = p & 31;
    const int q0 = p >> 5;              // 0..7
    const int qb = (lid >> 8) ? (15 - q0) : q0;

    const int tid = threadIdx.x, lane = tid & 63, wave = tid >> 6;
    const int g = lane >> 4, ln = lane & 15;

    const unsigned short* qp = q + (long)bh * Tt * Dd;
    const unsigned short* kp = k + (long)bh * Tt * Dd;
    const unsigned short* vp = vt + (long)bh * Dd * Tt;

    bf16x8 qf[2][4];
#pragma unroll
    for (int rf = 0; rf < 2; ++rf) {
        int t = qb * 128 + wave * 32 + rf * 16 + ln;
#pragma unroll
        for (int kc = 0; kc < 4; ++kc)
            qf[rf][kc] = *(const bf16x8*)(qp + (long)t * Dd + kc * 32 + g * 8);
    }

    f32x4 accO[2][8];
#pragma unroll
    for (int a = 0; a < 2; ++a)
#pragma unroll
        for (int b2 = 0; b2 < 8; ++b2)
#pragma unroll
            for (int e = 0; e < 4; ++e) accO[a][b2][e] = 0.f;

    float m_r[2][4], l_r[2][4];
#pragma unroll
    for (int a = 0; a < 2; ++a)
#pragma unroll
        for (int r = 0; r < 4; ++r) { m_r[a][r] = -1e30f; l_r[a][r] = 0.f; }

    const int ntiles = 2 * qb + 2;

    auto stage = [&](int buf, int tix) {
        const int j0 = tix * 64;
#pragma unroll
        for (int it = 0; it < 4; ++it) {
            int f = it * 256 + tid;
            int rk = f >> 4, ck = f & 15;
            gld16(kp + ((long)(j0 + rk) * Dd + ((ck ^ (rk & 7)) << 3)),
                  (char*)lds + buf * 16384 + f * 16);
            int rv = f >> 3, cv = f & 7;
            gld16(vp + ((long)rv * Tt + j0 + ((cv ^ (rv & 7)) << 3)),
                  (char*)lds + 32768 + buf * 16384 + f * 16);
        }
    };

    stage(0, 0);

    for (int tix = 0; tix < ntiles; ++tix) {
        const int cur = tix & 1;
        const int j0 = tix * 64;
        if (tix + 1 < ntiles) {
            stage(cur ^ 1, tix + 1);
            asm volatile("s_waitcnt vmcnt(8)" ::: "memory");
        } else {
            asm volatile("s_waitcnt vmcnt(0)" ::: "memory");
        }
        __builtin_amdgcn_s_barrier();

        const char* Kb = (const char*)lds + cur * 16384;
        const char* Vb = (const char*)lds + 32768 + cur * 16384;

        // S = Q K^T  (C-layout: row i = g*4+reg, col j = ln)
        f32x4 sa[2][4];
#pragma unroll
        for (int a = 0; a < 2; ++a)
#pragma unroll
            for (int b2 = 0; b2 < 4; ++b2)
#pragma unroll
                for (int e = 0; e < 4; ++e) sa[a][b2][e] = 0.f;
        __builtin_amdgcn_s_setprio(1);
#pragma unroll
        for (int ni = 0; ni < 4; ++ni) {
            bf16x8 kf[4];
#pragma unroll
            for (int kc = 0; kc < 4; ++kc) {
                int row = ni * 16 + ln;
                int byte = (row * 256 + kc * 64 + g * 16) ^ ((row & 7) << 4);
                kf[kc] = *(const bf16x8*)(Kb + byte);
            }
#pragma unroll
            for (int rf = 0; rf < 2; ++rf)
#pragma unroll
                for (int kc = 0; kc < 4; ++kc)
                    sa[rf][ni] = __builtin_amdgcn_mfma_f32_16x16x32_bf16(qf[rf][kc], kf[kc], sa[rf][ni], 0, 0, 0);
        }
        __builtin_amdgcn_s_setprio(0);

        // causal mask (scale pre-folded into q)
        const bool domask = (j0 + 63 > qb * 128);
        if (domask) {
#pragma unroll
            for (int rf = 0; rf < 2; ++rf)
#pragma unroll
                for (int ni = 0; ni < 4; ++ni)
#pragma unroll
                    for (int reg = 0; reg < 4; ++reg) {
                        int i = qb * 128 + wave * 32 + rf * 16 + g * 4 + reg;
                        int j = j0 + ni * 16 + ln;
                        if (j > i) sa[rf][ni][reg] = -1e30f;
                    }
        }

        // row max
        float mx[2][4];
#pragma unroll
        for (int rf = 0; rf < 2; ++rf)
#pragma unroll
            for (int reg = 0; reg < 4; ++reg) {
                float v = fmaxf(fmaxf(sa[rf][0][reg], sa[rf][1][reg]),
                                fmaxf(sa[rf][2][reg], sa[rf][3][reg]));
                v = fmaxf(v, __shfl_xor(v, 1, 64));
                v = fmaxf(v, __shfl_xor(v, 2, 64));
                v = fmaxf(v, __shfl_xor(v, 4, 64));
                v = fmaxf(v, __shfl_xor(v, 8, 64));
                mx[rf][reg] = v;
            }

        // defer-max (T13): rescale only if some row grew past THR=8 (exp2 domain)
        bool need = false;
#pragma unroll
        for (int rf = 0; rf < 2; ++rf)
#pragma unroll
            for (int reg = 0; reg < 4; ++reg)
                need = need || (mx[rf][reg] > m_r[rf][reg] + 8.f);

        if (__any(need)) {
#pragma unroll
            for (int rf = 0; rf < 2; ++rf)
#pragma unroll
                for (int reg = 0; reg < 4; ++reg) {
                    float mn = fmaxf(m_r[rf][reg], mx[rf][reg]);
                    float corr = fexp2(m_r[rf][reg] - mn);
                    m_r[rf][reg] = mn;
                    l_r[rf][reg] *= corr;
#pragma unroll
                    for (int ni = 0; ni < 8; ++ni) accO[rf][ni][reg] *= corr;
                }
        }

#pragma unroll
        for (int rf = 0; rf < 2; ++rf)
#pragma unroll
            for (int reg = 0; reg < 4; ++reg) {
                float rs = 0.f;
#pragma unroll
                for (int ni = 0; ni < 4; ++ni) {
                    float pv = fexp2(sa[rf][ni][reg] - m_r[rf][reg]);
                    sa[rf][ni][reg] = pv;
                    rs += pv;
                }
                rs += __shfl_xor(rs, 1, 64);
                rs += __shfl_xor(rs, 2, 64);
                rs += __shfl_xor(rs, 4, 64);
                rs += __shfl_xor(rs, 8, 64);
                l_r[rf][reg] += rs;
            }

        // P -> per-wave LDS (no barrier needed: same wave writes+reads)
        char* Pw = (char*)lds + 65536 + wave * 4096;
#pragma unroll
        for (int rf = 0; rf < 2; ++rf)
#pragma unroll
            for (int ni = 0; ni < 4; ++ni)
#pragma unroll
                for (int reg = 0; reg < 4; ++reg) {
                    int i = rf * 16 + g * 4 + reg;
                    int j = ni * 16 + ln;
                    int byte = (i * 128 + j * 2) ^ ((i & 7) << 4);
                    *(unsigned short*)(Pw + byte) = f2bf(sa[rf][ni][reg]);
                }
        asm volatile("s_waitcnt lgkmcnt(0)" ::: "memory");

        bf16x8 pf[2][2];
#pragma unroll
        for (int rf = 0; rf < 2; ++rf)
#pragma unroll
            for (int jc = 0; jc < 2; ++jc) {
                int i = rf * 16 + ln;
                int byte = (i * 128 + jc * 64 + g * 16) ^ ((i & 7) << 4);
                pf[rf][jc] = *(const bf16x8*)(Pw + byte);
            }
        __builtin_amdgcn_s_setprio(1);
#pragma unroll
        for (int ni = 0; ni < 8; ++ni)
#pragma unroll
            for (int jc = 0; jc < 2; ++jc) {
                int row = ni * 16 + ln;
                int byte = (row * 128 + jc * 64 + g * 16) ^ ((row & 7) << 4);
                bf16x8 vf = *(const bf16x8*)(Vb + byte);
#pragma unroll
                for (int rf = 0; rf < 2; ++rf)
                    accO[rf][ni] = __builtin_amdgcn_mfma_f32_16x16x32_bf16(pf[rf][jc], vf, accO[rf][ni], 0, 0, 0);
            }
        __builtin_amdgcn_s_setprio(0);

        asm volatile("" ::: "memory");
        __builtin_amdgcn_s_barrier();
    }

    // epilogue: o[b][t][h][d] = accO / l
    const int b = bh >> 4, hh = bh & 15;
#pragma unroll
    for (int rf = 0; rf < 2; ++rf)
#pragma unroll
        for (int reg = 0; reg < 4; ++reg) {
            float inv = 1.f / l_r[rf][reg];
            int t = qb * 128 + wave * 32 + rf * 16 + g * 4 + reg;
            long base = ((long)(b * Tt + t) * Hh + hh) * Dd;
#pragma unroll
            for (int ni = 0; ni < 8; ++ni) {
                int d = ni * 16 + ln;
                o[base + d] = f2bf(accO[rf][ni][reg] * inv);
            }
        }
}

// ---------------------------------------------------------------- output projection GEMM
__global__ __launch_bounds__(256) void out_gemm(
    const unsigned short* __restrict__ oIn,
    const unsigned short* __restrict__ woT,
    float* __restrict__ out) {
    __shared__ __align__(16) unsigned short smem[32768];
    const int bm = blockIdx.x, bn = blockIdx.y;
    const int tid = threadIdx.x;
    const int lane = tid & 63;
    const int wave = tid >> 6;
    const int g = lane >> 4;
    const int ln = lane & 15;

    const unsigned short* arow = oIn + (long)bm * 128 * Mm;
    const unsigned short* brow = woT + (long)bn * 128 * Mm;

    f32x4 acc[2][8];
#pragma unroll
    for (int a = 0; a < 2; ++a)
#pragma unroll
        for (int b2 = 0; b2 < 8; ++b2)
#pragma unroll
            for (int e = 0; e < 4; ++e) acc[a][b2][e] = 0.f;

    auto stage = [&](int buf, int kt) {
        const int k0 = kt * 64;
#pragma unroll
        for (int it = 0; it < 4; ++it) {
            int f = it * 256 + tid;
            int r = f >> 3, c = f & 7;
            long off = (long)r * Mm + k0 + ((c ^ (r & 7)) << 3);
            gld16(arow + off, (char*)smem + buf * 32768 + f * 16);
            gld16(brow + off, (char*)smem + buf * 32768 + 16384 + f * 16);
        }
    };

    stage(0, 0);

    for (int kt = 0; kt < Mm / 64; ++kt) {
        const int cur = kt & 1;
        if (kt + 1 < Mm / 64) {
            stage(cur ^ 1, kt + 1);
            asm volatile("s_waitcnt vmcnt(8)" ::: "memory");
        } else {
            asm volatile("s_waitcnt vmcnt(0)" ::: "memory");
        }
        __builtin_amdgcn_s_barrier();

        const char* Ab = (const char*)smem + cur * 32768;
        const char* Bv = Ab + 16384;
#pragma unroll
        for (int kc = 0; kc < 2; ++kc) {
            bf16x8 af[2];
#pragma unroll
            for (int rf = 0; rf < 2; ++rf) {
                int row = wave * 32 + rf * 16 + ln;
                int byte = (row * 128 + kc * 64 + g * 16) ^ ((row & 7) << 4);
                af[rf] = *(const bf16x8*)(Ab + byte);
            }
#pragma unroll
            for (int ni = 0; ni < 8; ++ni) {
                int row = ni * 16 + ln;
                int byte = (row * 128 + kc * 64 + g * 16) ^ ((row & 7) << 4);
                bf16x8 bfv = *(const bf16x8*)(Bv + byte);
#pragma unroll
                for (int rf = 0; rf < 2; ++rf)
                    acc[rf][ni] = __builtin_amdgcn_mfma_f32_16x16x32_bf16(af[rf], bfv, acc[rf][ni], 0, 0, 0);
            }
        }
        asm volatile("" ::: "memory");
        __builtin_amdgcn_s_barrier();
    }

#pragma unroll
    for (int rf = 0; rf < 2; ++rf)
#pragma unroll
        for (int reg = 0; reg < 4; ++reg) {
            long row = bm * 128 + wave * 32 + rf * 16 + g * 4 + reg;
#pragma unroll
            for (int ni = 0; ni < 8; ++ni)
                out[row * Mm + bn * 128 + ni * 16 + ln] = acc[rf][ni][reg];
        }
}

// ---------------------------------------------------------------- launch

extern "C" void kernel_launch(void* const* d_in, const int* in_sizes, int n_in,
                              void* d_out, int out_size, void* d_ws, size_t ws_size,
                              hipStream_t stream) {
    const float* x    = (const float*)d_in[0];
    const float* w_aq = (const float*)d_in[1];
    const float* w_ak = (const float*)d_in[2];
    const float* w_av = (const float*)d_in[3];
    const float* w_ao = (const float*)d_in[4];
    float* out = (float*)d_out;

    char* ws = (char*)d_ws;
    const long SZ_BTM = 16777216;   // B*T*M * 2B
    const long SZ_W   = 8388608;    // 2048*2048 * 2B
    unsigned short* xb  = (unsigned short*)(ws);
    unsigned short* qB  = (unsigned short*)(ws + SZ_BTM);
    unsigned short* kB  = (unsigned short*)(ws + 2 * SZ_BTM);
    unsigned short* vtB = (unsigned short*)(ws + 3 * SZ_BTM);
    unsigned short* oB  = (unsigned short*)(ws + 4 * SZ_BTM);
    unsigned short* wqT = (unsigned short*)(ws + 5 * SZ_BTM);
    unsigned short* wkT = (unsigned short*)(ws + 5 * SZ_BTM + SZ_W);
    unsigned short* wvT = (unsigned short*)(ws + 5 * SZ_BTM + 2 * SZ_W);
    unsigned short* woT = (unsigned short*)(ws + 5 * SZ_BTM + 3 * SZ_W);
    float* cosT = (float*)(ws + 5 * SZ_BTM + 4 * SZ_W);
    float* sinT = (float*)(ws + 5 * SZ_BTM + 4 * SZ_W + 524288);

    cvt_x_kernel<<<8192, 256, 0, stream>>>(x, xb);
    transpose_cvt<<<dim3(64, 4, 16), 256, 0, stream>>>(w_aq, wqT, 2048, 128, (long)2048 * 128, (long)128 * 2048);
    transpose_cvt<<<dim3(64, 4, 16), 256, 0, stream>>>(w_ak, wkT, 2048, 128, (long)2048 * 128, (long)128 * 2048);
    transpose_cvt<<<dim3(64, 4, 16), 256, 0, stream>>>(w_av, wvT, 2048, 128, (long)2048 * 128, (long)128 * 2048);
    transpose_cvt<<<dim3(64, 64, 1), 256, 0, stream>>>(w_ao, woT, 2048, 2048, 0, 0);
    rope_tab<<<512, 256, 0, stream>>>(cosT, sinT);

    proj_gemm<<<dim3(32, 16, 3), 256, 0, stream>>>(xb, wqT, wkT, wvT, qB, kB, vtB, cosT, sinT);
    attn_kernel<<<dim3(512), 256, 0, stream>>>(qB, kB, vtB, oB);
    out_gemm<<<dim3(32, 16), 256, 0, stream>>>(oB, woT, out);
}

// Round 3
// 263.147 us; speedup vs baseline: 1.6634x; 1.1985x over previous
//
#include <hip/hip_runtime.h>

#define Bb 2
#define Tt 2048
#define Mm 2048
#define Hh 16
#define Dd 128

typedef __attribute__((ext_vector_type(8))) short bf16x8;
typedef __attribute__((ext_vector_type(4))) float f32x4;
typedef __attribute__((ext_vector_type(16))) float f32x16;

__device__ __forceinline__ unsigned short f2bf(float f) {
    unsigned int u = __builtin_bit_cast(unsigned int, f);
    u += 0x7FFFu + ((u >> 16) & 1u);   // RNE
    return (unsigned short)(u >> 16);
}

__device__ __forceinline__ unsigned int cvt_pk_bf16(float lo, float hi) {
    unsigned int r;
    asm("v_cvt_pk_bf16_f32 %0, %1, %2" : "=v"(r) : "v"(lo), "v"(hi));
    return r;
}

__device__ __forceinline__ float fexp2(float x) { return __builtin_amdgcn_exp2f(x); }

__device__ __forceinline__ void gld16(const void* g, void* l) {
    __builtin_amdgcn_global_load_lds(
        (const __attribute__((address_space(1))) void*)g,
        (__attribute__((address_space(3))) void*)l, 16, 0, 0);
}

// ---------------------------------------------------------------- prep kernels

__global__ __launch_bounds__(256) void cvt_x_kernel(const float* __restrict__ x,
                                                    unsigned short* __restrict__ xb) {
    long i = ((long)blockIdx.x * 256 + threadIdx.x) * 4;
    float4 v = *(const float4*)(x + i);
    unsigned short r0 = f2bf(v.x), r1 = f2bf(v.y), r2 = f2bf(v.z), r3 = f2bf(v.w);
    unsigned int lo = (unsigned int)r0 | ((unsigned int)r1 << 16);
    unsigned int hi = (unsigned int)r2 | ((unsigned int)r3 << 16);
    uint2 packed; packed.x = lo; packed.y = hi;
    *(uint2*)(xb + i) = packed;
}

__global__ __launch_bounds__(256) void transpose_cvt(const float* __restrict__ in,
                                                     unsigned short* __restrict__ out,
                                                     int rows, int cols,
                                                     long in_slab, long out_slab) {
    __shared__ float tile[32][33];
    const float* ip = in + (long)blockIdx.z * in_slab;
    unsigned short* op = out + (long)blockIdx.z * out_slab;
    int r0 = blockIdx.x * 32, c0 = blockIdx.y * 32;
    int tx = threadIdx.x & 31, ty = threadIdx.x >> 5;
#pragma unroll
    for (int j = 0; j < 32; j += 8)
        tile[ty + j][tx] = ip[(long)(r0 + ty + j) * cols + c0 + tx];
    __syncthreads();
#pragma unroll
    for (int j = 0; j < 32; j += 8)
        op[(long)(c0 + ty + j) * rows + r0 + tx] = f2bf(tile[tx][ty + j]);
}

__global__ __launch_bounds__(256) void rope_tab(float* __restrict__ cosT,
                                                float* __restrict__ sinT) {
    int idx = blockIdx.x * 256 + threadIdx.x;   // T*64
    int t = idx >> 6, d = idx & 63;
    float freq = powf(10000.f, -(float)d / 64.f);
    float ang = (float)t * freq;
    sinT[idx] = sinf(ang);
    cosT[idx] = cosf(ang);
}

// ---------------------------------------------------------------- QKV projection GEMM
__global__ __launch_bounds__(256) void proj_gemm(
    const unsigned short* __restrict__ xb,
    const unsigned short* __restrict__ wqT,
    const unsigned short* __restrict__ wkT,
    const unsigned short* __restrict__ wvT,
    unsigned short* __restrict__ qO,
    unsigned short* __restrict__ kO,
    unsigned short* __restrict__ vtO,
    const float* __restrict__ cosT,
    const float* __restrict__ sinT) {
    __shared__ __align__(16) unsigned short smem[32768];   // 64 KB

    const int mode = blockIdx.z;
    const unsigned short* wT = (mode == 0) ? wqT : (mode == 1) ? wkT : wvT;
    const int bm = blockIdx.x;
    const int h  = blockIdx.y;
    const int tid = threadIdx.x;
    const int lane = tid & 63;
    const int wave = tid >> 6;
    const int g = lane >> 4;
    const int ln = lane & 15;

    const unsigned short* arow = xb + (long)bm * 128 * Mm;
    const unsigned short* brow = wT + (long)h * 128 * Mm;

    f32x4 acc[2][8];
#pragma unroll
    for (int a = 0; a < 2; ++a)
#pragma unroll
        for (int b2 = 0; b2 < 8; ++b2)
#pragma unroll
            for (int e = 0; e < 4; ++e) acc[a][b2][e] = 0.f;

    auto stage = [&](int buf, int kt) {
        const int k0 = kt * 64;
#pragma unroll
        for (int it = 0; it < 4; ++it) {
            int f = it * 256 + tid;
            int r = f >> 3, c = f & 7;
            long off = (long)r * Mm + k0 + ((c ^ (r & 7)) << 3);
            gld16(arow + off, (char*)smem + buf * 32768 + f * 16);
            gld16(brow + off, (char*)smem + buf * 32768 + 16384 + f * 16);
        }
    };

    stage(0, 0);

    for (int kt = 0; kt < Mm / 64; ++kt) {
        const int cur = kt & 1;
        if (kt + 1 < Mm / 64) {
            stage(cur ^ 1, kt + 1);
            asm volatile("s_waitcnt vmcnt(8)" ::: "memory");
        } else {
            asm volatile("s_waitcnt vmcnt(0)" ::: "memory");
        }
        __builtin_amdgcn_s_barrier();

        const char* Ab = (const char*)smem + cur * 32768;
        const char* Bv = Ab + 16384;
#pragma unroll
        for (int kc = 0; kc < 2; ++kc) {
            bf16x8 af[2];
#pragma unroll
            for (int rf = 0; rf < 2; ++rf) {
                int row = wave * 32 + rf * 16 + ln;
                int byte = (row * 128 + kc * 64 + g * 16) ^ ((row & 7) << 4);
                af[rf] = *(const bf16x8*)(Ab + byte);
            }
#pragma unroll
            for (int ni = 0; ni < 8; ++ni) {
                int row = ni * 16 + ln;
                int byte = (row * 128 + kc * 64 + g * 16) ^ ((row & 7) << 4);
                bf16x8 bfv = *(const bf16x8*)(Bv + byte);
#pragma unroll
                for (int rf = 0; rf < 2; ++rf)
                    acc[rf][ni] = __builtin_amdgcn_mfma_f32_16x16x32_bf16(af[rf], bfv, acc[rf][ni], 0, 0, 0);
            }
        }
        asm volatile("" ::: "memory");
        __builtin_amdgcn_s_barrier();
    }

    const int b  = bm >> 4;
    const int t0 = (bm & 15) * 128;

    if (mode < 2) {
        const float qscale = (mode == 0) ? 0.011271055f : 1.0f;  // log2(e)/D on q only
        unsigned short* out = (mode == 0) ? qO : kO;
        long hb = ((long)(b * Hh + h)) * Tt;
#pragma unroll
        for (int rf = 0; rf < 2; ++rf)
#pragma unroll
            for (int reg = 0; reg < 4; ++reg) {
                int i = wave * 32 + rf * 16 + g * 4 + reg;
                int t = t0 + i;
                long base = (hb + t) * Dd;
#pragma unroll
                for (int ni = 0; ni < 4; ++ni) {
                    int d = ni * 16 + ln;
                    float c = cosT[t * 64 + d];
                    float s = sinT[t * 64 + d];
                    float ev = acc[rf][ni][reg];
                    float od = acc[rf][ni + 4][reg];
                    out[base + d]      = f2bf((ev * c - od * s) * qscale);
                    out[base + d + 64] = f2bf((ev * s + od * c) * qscale);
                }
            }
    } else {
        __syncthreads();
#pragma unroll
        for (int rf = 0; rf < 2; ++rf)
#pragma unroll
            for (int ni = 0; ni < 8; ++ni)
#pragma unroll
                for (int reg = 0; reg < 4; ++reg) {
                    int i = wave * 32 + rf * 16 + g * 4 + reg;
                    int d = ni * 16 + ln;
                    int byte = (d * 256 + i * 2) ^ ((d & 7) << 4);
                    *(unsigned short*)((char*)smem + byte) = f2bf(acc[rf][ni][reg]);
                }
        __syncthreads();
        long hb = ((long)(b * Hh + h)) * Dd;
#pragma unroll
        for (int rep = 0; rep < 8; ++rep) {
            int d = rep * 16 + (tid >> 4);
            int tb = tid & 15;
            int byte = (d * 256 + tb * 16) ^ ((d & 7) << 4);
            uint4 v = *(const uint4*)((char*)smem + byte);
            *(uint4*)(vtO + ((hb + d) * Tt + t0 + tb * 8)) = v;
        }
    }
}

// ---------------------------------------------------------------- flash attention (swapped QK^T, 32x32x16)
// q (pre-scaled by log2e/D), k: (B,H,T,D) bf16 roped; vt: (B,H,D,T) bf16; o: (B,T,H,D) bf16
__global__ __launch_bounds__(256) void attn_kernel(
    const unsigned short* __restrict__ q,
    const unsigned short* __restrict__ k,
    const unsigned short* __restrict__ vt,
    unsigned short* __restrict__ o) {
    // Ks0 @0, Ks1 @16384, Vt0 @32768, Vt1 @49152 (bytes), 64 KB total
    __shared__ __align__(16) unsigned short lds[32768];

    // pairing remap: blocks n and n+256 get complementary qb
    const int lid = (int)blockIdx.x;
    const int p = lid & 255;
    const int bh = p & 31;
    const int q0 = p >> 5;
    const int qb = (lid >> 8) ? (15 - q0) : q0;

    const int tid = threadIdx.x, lane = tid & 63, wave = tid >> 6;
    const int h = lane >> 5, iln = lane & 31;

    const unsigned short* qp = q + (long)bh * Tt * Dd;
    const unsigned short* kp = k + (long)bh * Tt * Dd;
    const unsigned short* vp = vt + (long)bh * Dd * Tt;

    // Q fragments (B-operand): lane holds Q[t = qb*128+wave*32+iln][d = kk*16 + h*8 + e]
    const int i_g = qb * 128 + wave * 32 + iln;
    bf16x8 qf[8];
#pragma unroll
    for (int kk = 0; kk < 8; ++kk)
        qf[kk] = *(const bf16x8*)(qp + (long)i_g * Dd + kk * 16 + h * 8);

    f32x16 accO[4];
#pragma unroll
    for (int nb = 0; nb < 4; ++nb)
#pragma unroll
        for (int e = 0; e < 16; ++e) accO[nb][e] = 0.f;

    float m_r = -1e30f, l_r = 0.f;

    const int ntiles = 2 * qb + 2;

    auto stage = [&](int buf, int tix) {
        const int j0s = tix * 64;
#pragma unroll
        for (int it = 0; it < 4; ++it) {
            int f = it * 256 + tid;
            int rk = f >> 4, ck = f & 15;
            gld16(kp + ((long)(j0s + rk) * Dd + ((ck ^ (rk & 7)) << 3)),
                  (char*)lds + buf * 16384 + f * 16);
            int rv = f >> 3, cv = f & 7;
            gld16(vp + ((long)rv * Tt + j0s + ((cv ^ (rv & 7)) << 3)),
                  (char*)lds + 32768 + buf * 16384 + f * 16);
        }
    };

    stage(0, 0);

    for (int tix = 0; tix < ntiles; ++tix) {
        const int cur = tix & 1;
        const int j0 = tix * 64;
        if (tix + 1 < ntiles) {
            stage(cur ^ 1, tix + 1);
            asm volatile("s_waitcnt vmcnt(8)" ::: "memory");
        } else {
            asm volatile("s_waitcnt vmcnt(0)" ::: "memory");
        }
        __builtin_amdgcn_s_barrier();

        const char* Kb = (const char*)lds + cur * 16384;
        const char* Vb = (const char*)lds + 32768 + cur * 16384;

        // S^T = K·Q^T : sacc[mb], C-layout: col = iln = q-row i, row = j = mb*32+(reg&3)+8*(reg>>2)+4*h
        f32x16 sacc[2];
#pragma unroll
        for (int mb = 0; mb < 2; ++mb)
#pragma unroll
            for (int e = 0; e < 16; ++e) sacc[mb][e] = 0.f;

        __builtin_amdgcn_s_setprio(1);
#pragma unroll
        for (int mb = 0; mb < 2; ++mb) {
            int row = mb * 32 + iln;
            const char* Kr = Kb + row * 256;
            int sw = row & 7;
#pragma unroll
            for (int kk = 0; kk < 8; ++kk) {
                bf16x8 kf = *(const bf16x8*)(Kr + 16 * ((kk * 2 + h) ^ sw));
                sacc[mb] = __builtin_amdgcn_mfma_f32_32x32x16_bf16(kf, qf[kk], sacc[mb], 0, 0, 0);
            }
        }
        __builtin_amdgcn_s_setprio(0);

        // causal mask: each lane owns q-row i_g; j = j0 + mb*32 + (reg&3)+8*(reg>>2)+4*h
        const bool domask = (j0 + 63 > qb * 128);
        if (domask) {
#pragma unroll
            for (int mb = 0; mb < 2; ++mb)
#pragma unroll
                for (int reg = 0; reg < 16; ++reg) {
                    int j = j0 + mb * 32 + (reg & 3) + 8 * (reg >> 2) + 4 * h;
                    if (j > i_g) sacc[mb][reg] = -1e30f;
                }
        }

        // row max: in-lane balanced tree + one cross-half combine
        float red[16];
#pragma unroll
        for (int r = 0; r < 16; ++r) red[r] = fmaxf(sacc[0][r], sacc[1][r]);
#pragma unroll
        for (int s = 8; s >= 1; s >>= 1)
#pragma unroll
            for (int r = 0; r < s; ++r) red[r] = fmaxf(red[r], red[r + s]);
        float mx = fmaxf(red[0], __shfl_xor(red[0], 32, 64));

        // defer-max (T13): THR=8 in exp2 domain
        if (__any(mx > m_r + 8.f)) {
            float mn = fmaxf(m_r, mx);
            float corr = fexp2(m_r - mn);
            m_r = mn;
            l_r *= corr;
#pragma unroll
            for (int reg = 0; reg < 16; ++reg) {
                int rrow = (reg & 3) + 8 * (reg >> 2) + 4 * h;
                float c = __shfl(corr, rrow, 64);
#pragma unroll
                for (int nb = 0; nb < 4; ++nb) accO[nb][reg] *= c;
            }
        }

        // P = exp2(S - m), in-lane sum
        float pe[2][16];
#pragma unroll
        for (int mb = 0; mb < 2; ++mb)
#pragma unroll
            for (int r = 0; r < 16; ++r) pe[mb][r] = fexp2(sacc[mb][r] - m_r);
        float sr[16];
#pragma unroll
        for (int r = 0; r < 16; ++r) sr[r] = pe[0][r] + pe[1][r];
#pragma unroll
        for (int s = 8; s >= 1; s >>= 1)
#pragma unroll
            for (int r = 0; r < s; ++r) sr[r] += sr[r + s];
        l_r += sr[0] + __shfl_xor(sr[0], 32, 64);

        // P -> bf16 pairs: pu[mb][t] holds j-pair base jp = mb*32 + 2*(t&1) + 8*(t>>1) + 4*h
        unsigned int pu[2][8];
#pragma unroll
        for (int mb = 0; mb < 2; ++mb)
#pragma unroll
            for (int t = 0; t < 8; ++t)
                pu[mb][t] = cvt_pk_bf16(pe[mb][2 * t], pe[mb][2 * t + 1]);

        // exchange halves: send pairs with (t>>1)&1 != h
        unsigned int rv[2][4];
#pragma unroll
        for (int mb = 0; mb < 2; ++mb)
#pragma unroll
            for (int u = 0; u < 4; ++u) {
                unsigned int sv = h ? pu[mb][(u & 1) + 4 * (u >> 1)]
                                    : pu[mb][2 + (u & 1) + 4 * (u >> 1)];
                rv[mb][u] = __shfl_xor(sv, 32, 64);
            }

        // O += P·V : A-frag for kk2 needs P[i][j = kk2*16 + h*8 + e]
        __builtin_amdgcn_s_setprio(1);
#pragma unroll
        for (int kk2 = 0; kk2 < 4; ++kk2) {
            const int mb = kk2 >> 1, c2 = kk2 & 1;
            unsigned int w0 = h ? rv[mb][2 * c2 + 0] : pu[mb][4 * c2 + 0];
            unsigned int w1 = h ? rv[mb][2 * c2 + 1] : pu[mb][4 * c2 + 1];
            unsigned int w2 = h ? pu[mb][4 * c2 + 2] : rv[mb][2 * c2 + 0];
            unsigned int w3 = h ? pu[mb][4 * c2 + 3] : rv[mb][2 * c2 + 1];
            uint4 aw; aw.x = w0; aw.y = w1; aw.z = w2; aw.w = w3;
            bf16x8 af = __builtin_bit_cast(bf16x8, aw);
#pragma unroll
            for (int nb = 0; nb < 4; ++nb) {
                int d = nb * 32 + iln;
                int byte = d * 128 + 16 * ((kk2 * 2 + h) ^ (d & 7));
                bf16x8 vf = *(const bf16x8*)(Vb + byte);
                accO[nb] = __builtin_amdgcn_mfma_f32_32x32x16_bf16(af, vf, accO[nb], 0, 0, 0);
            }
        }
        __builtin_amdgcn_s_setprio(0);

        asm volatile("" ::: "memory");
        __builtin_amdgcn_s_barrier();
    }

    // epilogue: o[b][t][h][d] = accO / l  (accO row = (reg&3)+8*(reg>>2)+4*h, col d = nb*32+iln)
    const int b = bh >> 4, hh = bh & 15;
    float invl = 1.f / l_r;
#pragma unroll
    for (int reg = 0; reg < 16; ++reg) {
        int rrow = (reg & 3) + 8 * (reg >> 2) + 4 * h;
        float iv = __shfl(invl, rrow, 64);
        int t = qb * 128 + wave * 32 + rrow;
        long base = ((long)(b * Tt + t) * Hh + hh) * Dd;
#pragma unroll
        for (int nb = 0; nb < 4; ++nb)
            o[base + nb * 32 + iln] = f2bf(accO[nb][reg] * iv);
    }
}

// ---------------------------------------------------------------- output projection GEMM
__global__ __launch_bounds__(256) void out_gemm(
    const unsigned short* __restrict__ oIn,
    const unsigned short* __restrict__ woT,
    float* __restrict__ out) {
    __shared__ __align__(16) unsigned short smem[32768];
    const int bm = blockIdx.x, bn = blockIdx.y;
    const int tid = threadIdx.x;
    const int lane = tid & 63;
    const int wave = tid >> 6;
    const int g = lane >> 4;
    const int ln = lane & 15;

    const unsigned short* arow = oIn + (long)bm * 128 * Mm;
    const unsigned short* brow = woT + (long)bn * 128 * Mm;

    f32x4 acc[2][8];
#pragma unroll
    for (int a = 0; a < 2; ++a)
#pragma unroll
        for (int b2 = 0; b2 < 8; ++b2)
#pragma unroll
            for (int e = 0; e < 4; ++e) acc[a][b2][e] = 0.f;

    auto stage = [&](int buf, int kt) {
        const int k0 = kt * 64;
#pragma unroll
        for (int it = 0; it < 4; ++it) {
            int f = it * 256 + tid;
            int r = f >> 3, c = f & 7;
            long off = (long)r * Mm + k0 + ((c ^ (r & 7)) << 3);
            gld16(arow + off, (char*)smem + buf * 32768 + f * 16);
            gld16(brow + off, (char*)smem + buf * 32768 + 16384 + f * 16);
        }
    };

    stage(0, 0);

    for (int kt = 0; kt < Mm / 64; ++kt) {
        const int cur = kt & 1;
        if (kt + 1 < Mm / 64) {
            stage(cur ^ 1, kt + 1);
            asm volatile("s_waitcnt vmcnt(8)" ::: "memory");
        } else {
            asm volatile("s_waitcnt vmcnt(0)" ::: "memory");
        }
        __builtin_amdgcn_s_barrier();

        const char* Ab = (const char*)smem + cur * 32768;
        const char* Bv = Ab + 16384;
#pragma unroll
        for (int kc = 0; kc < 2; ++kc) {
            bf16x8 af[2];
#pragma unroll
            for (int rf = 0; rf < 2; ++rf) {
                int row = wave * 32 + rf * 16 + ln;
                int byte = (row * 128 + kc * 64 + g * 16) ^ ((row & 7) << 4);
                af[rf] = *(const bf16x8*)(Ab + byte);
            }
#pragma unroll
            for (int ni = 0; ni < 8; ++ni) {
                int row = ni * 16 + ln;
                int byte = (row * 128 + kc * 64 + g * 16) ^ ((row & 7) << 4);
                bf16x8 bfv = *(const bf16x8*)(Bv + byte);
#pragma unroll
                for (int rf = 0; rf < 2; ++rf)
                    acc[rf][ni] = __builtin_amdgcn_mfma_f32_16x16x32_bf16(af[rf], bfv, acc[rf][ni], 0, 0, 0);
            }
        }
        asm volatile("" ::: "memory");
        __builtin_amdgcn_s_barrier();
    }

#pragma unroll
    for (int rf = 0; rf < 2; ++rf)
#pragma unroll
        for (int reg = 0; reg < 4; ++reg) {
            long row = bm * 128 + wave * 32 + rf * 16 + g * 4 + reg;
#pragma unroll
            for (int ni = 0; ni < 8; ++ni)
                out[row * Mm + bn * 128 + ni * 16 + ln] = acc[rf][ni][reg];
        }
}

// ---------------------------------------------------------------- launch

extern "C" void kernel_launch(void* const* d_in, const int* in_sizes, int n_in,
                              void* d_out, int out_size, void* d_ws, size_t ws_size,
                              hipStream_t stream) {
    const float* x    = (const float*)d_in[0];
    const float* w_aq = (const float*)d_in[1];
    const float* w_ak = (const float*)d_in[2];
    const float* w_av = (const float*)d_in[3];
    const float* w_ao = (const float*)d_in[4];
    float* out = (float*)d_out;

    char* ws = (char*)d_ws;
    const long SZ_BTM = 16777216;   // B*T*M * 2B
    const long SZ_W   = 8388608;    // 2048*2048 * 2B
    unsigned short* xb  = (unsigned short*)(ws);
    unsigned short* qB  = (unsigned short*)(ws + SZ_BTM);
    unsigned short* kB  = (unsigned short*)(ws + 2 * SZ_BTM);
    unsigned short* vtB = (unsigned short*)(ws + 3 * SZ_BTM);
    unsigned short* oB  = (unsigned short*)(ws + 4 * SZ_BTM);
    unsigned short* wqT = (unsigned short*)(ws + 5 * SZ_BTM);
    unsigned short* wkT = (unsigned short*)(ws + 5 * SZ_BTM + SZ_W);
    unsigned short* wvT = (unsigned short*)(ws + 5 * SZ_BTM + 2 * SZ_W);
    unsigned short* woT = (unsigned short*)(ws + 5 * SZ_BTM + 3 * SZ_W);
    float* cosT = (float*)(ws + 5 * SZ_BTM + 4 * SZ_W);
    float* sinT = (float*)(ws + 5 * SZ_BTM + 4 * SZ_W + 524288);

    cvt_x_kernel<<<8192, 256, 0, stream>>>(x, xb);
    transpose_cvt<<<dim3(64, 4, 16), 256, 0, stream>>>(w_aq, wqT, 2048, 128, (long)2048 * 128, (long)128 * 2048);
    transpose_cvt<<<dim3(64, 4, 16), 256, 0, stream>>>(w_ak, wkT, 2048, 128, (long)2048 * 128, (long)128 * 2048);
    transpose_cvt<<<dim3(64, 4, 16), 256, 0, stream>>>(w_av, wvT, 2048, 128, (long)2048 * 128, (long)128 * 2048);
    transpose_cvt<<<dim3(64, 64, 1), 256, 0, stream>>>(w_ao, woT, 2048, 2048, 0, 0);
    rope_tab<<<512, 256, 0, stream>>>(cosT, sinT);

    proj_gemm<<<dim3(32, 16, 3), 256, 0, stream>>>(xb, wqT, wkT, wvT, qB, kB, vtB, cosT, sinT);
    attn_kernel<<<dim3(512), 256, 0, stream>>>(qB, kB, vtB, oB);
    out_gemm<<<dim3(32, 16), 256, 0, stream>>>(oB, woT, out);
}

// Round 4
// 257.667 us; speedup vs baseline: 1.6988x; 1.0213x over previous
//
#include <hip/hip_runtime.h>

#define Bb 2
#define Tt 2048
#define Mm 2048
#define Hh 16
#define Dd 128
#define PROJ_NT 32   // K tiles of 64

typedef __attribute__((ext_vector_type(8))) short bf16x8;
typedef __attribute__((ext_vector_type(4))) float f32x4;
typedef __attribute__((ext_vector_type(16))) float f32x16;

__device__ __forceinline__ unsigned short f2bf(float f) {
    unsigned int u = __builtin_bit_cast(unsigned int, f);
    u += 0x7FFFu + ((u >> 16) & 1u);   // RNE
    return (unsigned short)(u >> 16);
}

__device__ __forceinline__ unsigned int cvt_pk_bf16(float lo, float hi) {
    unsigned int r;
    asm("v_cvt_pk_bf16_f32 %0, %1, %2" : "=v"(r) : "v"(lo), "v"(hi));
    return r;
}

__device__ __forceinline__ float fexp2(float x) { return __builtin_amdgcn_exp2f(x); }

__device__ __forceinline__ void gld16(const void* g, void* l) {
    __builtin_amdgcn_global_load_lds(
        (const __attribute__((address_space(1))) void*)g,
        (__attribute__((address_space(3))) void*)l, 16, 0, 0);
}

// ---------------------------------------------------------------- prep kernels

__global__ __launch_bounds__(256) void cvt_x_kernel(const float* __restrict__ x,
                                                    unsigned short* __restrict__ xb) {
    long i = ((long)blockIdx.x * 256 + threadIdx.x) * 4;
    float4 v = *(const float4*)(x + i);
    unsigned short r0 = f2bf(v.x), r1 = f2bf(v.y), r2 = f2bf(v.z), r3 = f2bf(v.w);
    unsigned int lo = (unsigned int)r0 | ((unsigned int)r1 << 16);
    unsigned int hi = (unsigned int)r2 | ((unsigned int)r3 << 16);
    uint2 packed; packed.x = lo; packed.y = hi;
    *(uint2*)(xb + i) = packed;
}

// plain transpose (for w_ao): in rows x cols fp32 -> out cols x rows bf16
__global__ __launch_bounds__(256) void transpose_cvt(const float* __restrict__ in,
                                                     unsigned short* __restrict__ out,
                                                     int rows, int cols,
                                                     long in_slab, long out_slab) {
    __shared__ float tile[32][33];
    const float* ip = in + (long)blockIdx.z * in_slab;
    unsigned short* op = out + (long)blockIdx.z * out_slab;
    int r0 = blockIdx.x * 32, c0 = blockIdx.y * 32;
    int tx = threadIdx.x & 31, ty = threadIdx.x >> 5;
#pragma unroll
    for (int j = 0; j < 32; j += 8)
        tile[ty + j][tx] = ip[(long)(r0 + ty + j) * cols + c0 + tx];
    __syncthreads();
#pragma unroll
    for (int j = 0; j < 32; j += 8)
        op[(long)(c0 + ty + j) * rows + r0 + tx] = f2bf(tile[tx][ty + j]);
}

// qkv weights: transpose + within-head column interleave so RoPE pairs (d, d+64)
// land in adjacent 16-col blocks: p = ( ((d>>4)&3)*2 + (d>>6) )*16 + (d&15)
__global__ __launch_bounds__(256) void transpose_cvt_qkv(
    const float* __restrict__ wq, const float* __restrict__ wk, const float* __restrict__ wv,
    unsigned short* __restrict__ outBase) {
    __shared__ float tile[32][33];
    const int z = blockIdx.z;             // 0..47
    const int which = z >> 4, slab = z & 15;
    const float* ip = (which == 0 ? wq : which == 1 ? wk : wv) + (long)slab * 2048 * 128;
    unsigned short* op = outBase + (long)which * 4194304 + (long)slab * 128 * 2048;
    int r0 = blockIdx.x * 32, c0 = blockIdx.y * 32;   // r over k(2048), c over d(128)
    int tx = threadIdx.x & 31, ty = threadIdx.x >> 5;
#pragma unroll
    for (int j = 0; j < 32; j += 8)
        tile[ty + j][tx] = ip[(long)(r0 + ty + j) * 128 + c0 + tx];
    __syncthreads();
#pragma unroll
    for (int j = 0; j < 32; j += 8) {
        int d = c0 + ty + j;
        int p = (((d >> 4) & 3) * 2 + (d >> 6)) * 16 + (d & 15);
        op[(long)p * 2048 + r0 + tx] = f2bf(tile[tx][ty + j]);
    }
}

__global__ __launch_bounds__(256) void rope_tab(float* __restrict__ cosT,
                                                float* __restrict__ sinT) {
    int idx = blockIdx.x * 256 + threadIdx.x;   // T*64
    int t = idx >> 6, d = idx & 63;
    float freq = powf(10000.f, -(float)d / 64.f);
    float ang = (float)t * freq;
    sinT[idx] = sinf(ang);
    cosT[idx] = cosf(ang);
}

// ---------------------------------------------------------------- 256x{256,128} 4-phase GEMM sub-tile
// A = xb panel (256 x 2048 bf16), B = permuted wT rows (BN x 2048).
// 8 waves as 2M x 4N; per-wave 128 x (BN/4). Double-buffered 128KB LDS,
// 4 phases per K-tile with counted vmcnt (loads stay in flight across barriers).
template <int BN>
__device__ __forceinline__ void do_subtile(
    const unsigned short* __restrict__ Asrc,
    const unsigned short* __restrict__ Bsrc,
    char* lds, int mode, int off, int bm,
    unsigned short* __restrict__ qO, unsigned short* __restrict__ kO,
    unsigned short* __restrict__ vtO,
    const float* __restrict__ cosT, const float* __restrict__ sinT,
    int tid) {
    const int lane = tid & 63, wave = tid >> 6;
    const int wm = wave >> 2, wn = wave & 3;   // 2M x 4N
    const int ln = lane & 15, g4 = lane >> 4;
    constexpr int NF = BN / 64;   // 4 wide, 2 narrow
    constexpr int NQ = (BN == 256) ? 2 : 1;

    f32x4 acc[8][NF];
#pragma unroll
    for (int a = 0; a < 8; ++a)
#pragma unroll
        for (int b2 = 0; b2 < NF; ++b2)
#pragma unroll
            for (int e = 0; e < 4; ++e) acc[a][b2][e] = 0.f;

    // ---- stage events (linear LDS dest, pre-swizzled global source)
    auto stA = [&](char* buf, int h, int kt) {   // 16KB: A rows with (r>>6)&1==h
#pragma unroll
        for (int l = 0; l < 2; ++l) {
            int f = l * 512 + tid;
            int s = ((f >> 9) << 1) + h;           // stripe64
            int q = f & 511;
            int r = q >> 3;
            gld16(Asrc + (long)(s * 64 + r) * Mm + kt * 64 + (((q & 7) ^ (r & 7)) << 3),
                  buf + s * 8192 + q * 16);
        }
    };
    auto stB = [&](char* buf, int h, int kt) {
        if constexpr (BN == 256) {                  // 16KB: cols with (c>>5)&1==h
#pragma unroll
            for (int l = 0; l < 2; ++l) {
                int f = l * 512 + tid;
                int s = ((f >> 8) << 1) + h;        // stripe32
                int q = f & 255;
                int r = q >> 3;
                gld16(Bsrc + (long)(s * 32 + r) * Mm + kt * 64 + (((q & 7) ^ (r & 7)) << 3),
                      buf + 32768 + s * 4096 + q * 16);
            }
        } else {                                    // 8KB: cols with (c>>4)&1==h
            int f = tid;
            int s = ((f >> 7) << 1) + h;            // stripe16
            int q = f & 127;
            int r = q >> 3;
            gld16(Bsrc + (long)(s * 16 + r) * Mm + kt * 64 + (((q & 7) ^ (r & 7)) << 3),
                  buf + 32768 + s * 2048 + q * 16);
        }
    };

    // ---- fragment readers (swizzled)
    auto rdA = [&](const char* buf, int MH, int mf, int kk) -> bf16x8 {
        int row = wm * 128 + MH * 64 + mf * 16 + ln;
        int byte = (row >> 6) * 8192 + ((((row & 63) * 128) + (kk * 4 + g4) * 16) ^ ((row & 7) << 4));
        return *(const bf16x8*)(buf + byte);
    };
    auto rdB = [&](const char* buf, int NH, int nf, int kk) -> bf16x8 {
        if constexpr (BN == 256) {
            int col = wn * 64 + NH * 32 + nf * 16 + ln;
            int byte = 32768 + (col >> 5) * 4096 +
                       ((((col & 31) * 128) + (kk * 4 + g4) * 16) ^ ((col & 7) << 4));
            return *(const bf16x8*)(buf + byte);
        } else {
            int col = wn * 32 + NH * 16 + ln;
            int byte = 32768 + (col >> 4) * 2048 +
                       ((((col & 15) * 128) + (kk * 4 + g4) * 16) ^ ((col & 7) << 4));
            return *(const bf16x8*)(buf + byte);
        }
    };

    auto phase = [&](const char* bc, int MH, int NH) {
        bf16x8 af[4][2];
#pragma unroll
        for (int mf = 0; mf < 4; ++mf)
#pragma unroll
            for (int kk = 0; kk < 2; ++kk) af[mf][kk] = rdA(bc, MH, mf, kk);
        bf16x8 bfr[NQ][2];
#pragma unroll
        for (int nf = 0; nf < NQ; ++nf)
#pragma unroll
            for (int kk = 0; kk < 2; ++kk) bfr[nf][kk] = rdB(bc, NH, nf, kk);
        __builtin_amdgcn_s_setprio(1);
#pragma unroll
        for (int mf = 0; mf < 4; ++mf)
#pragma unroll
            for (int nf = 0; nf < NQ; ++nf)
#pragma unroll
                for (int kk = 0; kk < 2; ++kk)
                    acc[MH * 4 + mf][NH * NQ + nf] = __builtin_amdgcn_mfma_f32_16x16x32_bf16(
                        af[mf][kk], bfr[nf][kk], acc[MH * 4 + mf][NH * NQ + nf], 0, 0, 0);
        __builtin_amdgcn_s_setprio(0);
    };

    // ---- prologue: stream order B_0^0, A_1^0, A_0^0, B_1^0, B_0^1, A_1^1
    stB(lds, 0, 0); stA(lds, 1, 0); stA(lds, 0, 0); stB(lds, 1, 0);
    stB(lds + 65536, 0, 1); stA(lds + 65536, 1, 1);

    // ---- main loop. Phases: (0,0) (1,0) (1,1) (0,1).
    // Stages: ph0 -> A_0^{t+1}, ph1 -> B_1^{t+1}, ph2 -> B_0^{t+2}, ph3 -> A_1^{t+2}
    for (int t = 0; t < PROJ_NT; ++t) {
        char* bc = lds + (t & 1) * 65536;
        char* bo = lds + (((t & 1) ^ 1) * 65536);
        const int tn1 = (t + 1 < PROJ_NT) ? t + 1 : PROJ_NT - 1;
        const int tn2 = (t + 2 < PROJ_NT) ? t + 2 : PROJ_NT - 1;

        stA(bo, 0, tn1);
        if constexpr (BN == 256) asm volatile("s_waitcnt vmcnt(8)" ::: "memory");
        else                     asm volatile("s_waitcnt vmcnt(6)" ::: "memory");
        asm volatile("s_barrier" ::: "memory");
        phase(bc, 0, 0);
        asm volatile("s_barrier" ::: "memory");

        stB(bo, 1, tn1);
        asm volatile("s_barrier" ::: "memory");
        phase(bc, 1, 0);
        asm volatile("s_barrier" ::: "memory");

        stB(bc, 0, tn2);
        if constexpr (BN == 256) asm volatile("s_waitcnt vmcnt(10)" ::: "memory");
        else                     asm volatile("s_waitcnt vmcnt(7)" ::: "memory");
        asm volatile("s_barrier" ::: "memory");
        phase(bc, 1, 1);
        asm volatile("s_barrier" ::: "memory");

        stA(bc, 1, tn2);
        asm volatile("s_barrier" ::: "memory");
        phase(bc, 0, 1);
        asm volatile("s_barrier" ::: "memory");
    }
    asm volatile("s_waitcnt vmcnt(0)" ::: "memory");
    __syncthreads();

    // ---- epilogue
    const int b = bm >> 3;
    const int t0w = (bm & 7) * 256 + wm * 128;
    const int headL = (off & 2047) >> 7;

    if (mode < 2) {
        const float qs = (mode == 0) ? 0.011271055f : 1.0f;  // log2(e)/D on q only
        unsigned short* out = (mode == 0) ? qO : kO;
#pragma unroll
        for (int MF = 0; MF < 8; ++MF)
#pragma unroll
            for (int NP = 0; NP < NF; NP += 2) {
                int head, j16;
                if constexpr (BN == 256) { head = headL + (wn >> 1); j16 = (wn & 1) * 2 + (NP >> 1); }
                else                     { head = headL; j16 = wn; }
                int dlo = j16 * 16 + ln;
#pragma unroll
                for (int e = 0; e < 4; ++e) {
                    int t = t0w + MF * 16 + g4 * 4 + e;
                    float c = cosT[t * 64 + dlo], s = sinT[t * 64 + dlo];
                    float ev = acc[MF][NP][e], od = acc[MF][NP + 1][e];
                    long base = (((long)(b * Hh + head)) * Tt + t) * Dd;
                    out[base + dlo]      = f2bf((ev * c - od * s) * qs);
                    out[base + dlo + 64] = f2bf((ev * s + od * c) * qs);
                }
            }
    } else {
        // V: per-wave LDS transpose patch [dslot][128 t]
        constexpr int PS = (BN == 256) ? 16384 : 8192;
        char* patch = lds + wave * PS;
#pragma unroll
        for (int MF = 0; MF < 8; ++MF)
#pragma unroll
            for (int NFi = 0; NFi < NF; ++NFi) {
                int dslot = NFi * 16 + ln;
#pragma unroll
                for (int e = 0; e < 4; ++e) {
                    int tloc = MF * 16 + g4 * 4 + e;
                    int byte = (dslot * 256 + tloc * 2) ^ ((dslot & 7) << 4);
                    *(unsigned short*)(patch + byte) = f2bf(acc[MF][NFi][e]);
                }
            }
        constexpr int NPASS = (BN == 256) ? 16 : 8;
#pragma unroll
        for (int p = 0; p < NPASS; ++p) {
            int dslot = p * 4 + g4;
            int t8 = ln;
            int byte = (dslot * 256 + t8 * 16) ^ ((dslot & 7) << 4);
            uint4 v = *(const uint4*)(patch + byte);
            int NFi = dslot >> 4;
            int head, j16;
            if constexpr (BN == 256) { head = headL + (wn >> 1); j16 = (wn & 1) * 2 + (NFi >> 1); }
            else                     { head = headL; j16 = wn; }
            int d = (NFi & 1) * 64 + j16 * 16 + (dslot & 15);
            long baseo = (((long)(b * Hh + head)) * Dd + d) * Tt + t0w + t8 * 8;
            *(uint4*)(vtO + baseo) = v;
        }
    }
}

// block = 256 rows x 384 concatenated-N cols, split 256+128 (order avoids mode straddle)
__global__ __launch_bounds__(512, 2) void proj_gemm2(
    const unsigned short* __restrict__ xb,
    const unsigned short* __restrict__ wqT,
    const unsigned short* __restrict__ wkT,
    const unsigned short* __restrict__ wvT,
    unsigned short* __restrict__ qO,
    unsigned short* __restrict__ kO,
    unsigned short* __restrict__ vtO,
    const float* __restrict__ cosT,
    const float* __restrict__ sinT) {
    __shared__ __align__(16) char lds[131072];
    const int bm = blockIdx.x, bn = blockIdx.y;
    const int tid = threadIdx.x;
    const int s = bn * 384;
    const bool swap = ((s & 2047) == 1920);
    const int offw = swap ? s + 128 : s;
    const int offn = swap ? s : s + 256;
    const unsigned short* Asrc = xb + (long)bm * 256 * Mm;

    {
        int mode = offw >> 11;
        const unsigned short* wT = (mode == 0) ? wqT : (mode == 1) ? wkT : wvT;
        do_subtile<256>(Asrc, wT + (long)(offw & 2047) * Mm, lds, mode, offw, bm,
                        qO, kO, vtO, cosT, sinT, tid);
    }
    __syncthreads();
    {
        int mode = offn >> 11;
        const unsigned short* wT = (mode == 0) ? wqT : (mode == 1) ? wkT : wvT;
        do_subtile<128>(Asrc, wT + (long)(offn & 2047) * Mm, lds, mode, offn, bm,
                        qO, kO, vtO, cosT, sinT, tid);
    }
}

// ---------------------------------------------------------------- flash attention (swapped QK^T, 32x32x16)
__global__ __launch_bounds__(256) void attn_kernel(
    const unsigned short* __restrict__ q,
    const unsigned short* __restrict__ k,
    const unsigned short* __restrict__ vt,
    unsigned short* __restrict__ o) {
    __shared__ __align__(16) unsigned short lds[32768];

    const int lid = (int)blockIdx.x;
    const int p = lid & 255;
    const int bh = p & 31;
    const int q0 = p >> 5;
    const int qb = (lid >> 8) ? (15 - q0) : q0;

    const int tid = threadIdx.x, lane = tid & 63, wave = tid >> 6;
    const int h = lane >> 5, iln = lane & 31;

    const unsigned short* qp = q + (long)bh * Tt * Dd;
    const unsigned short* kp = k + (long)bh * Tt * Dd;
    const unsigned short* vp = vt + (long)bh * Dd * Tt;

    const int i_g = qb * 128 + wave * 32 + iln;
    bf16x8 qf[8];
#pragma unroll
    for (int kk = 0; kk < 8; ++kk)
        qf[kk] = *(const bf16x8*)(qp + (long)i_g * Dd + kk * 16 + h * 8);

    f32x16 accO[4];
#pragma unroll
    for (int nb = 0; nb < 4; ++nb)
#pragma unroll
        for (int e = 0; e < 16; ++e) accO[nb][e] = 0.f;

    float m_r = -1e30f, l_r = 0.f;
    const int ntiles = 2 * qb + 2;

    auto stage = [&](int buf, int tix) {
        const int j0s = tix * 64;
#pragma unroll
        for (int it = 0; it < 4; ++it) {
            int f = it * 256 + tid;
            int rk = f >> 4, ck = f & 15;
            gld16(kp + ((long)(j0s + rk) * Dd + ((ck ^ (rk & 7)) << 3)),
                  (char*)lds + buf * 16384 + f * 16);
            int rv = f >> 3, cv = f & 7;
            gld16(vp + ((long)rv * Tt + j0s + ((cv ^ (rv & 7)) << 3)),
                  (char*)lds + 32768 + buf * 16384 + f * 16);
        }
    };

    stage(0, 0);

    for (int tix = 0; tix < ntiles; ++tix) {
        const int cur = tix & 1;
        const int j0 = tix * 64;
        if (tix + 1 < ntiles) {
            stage(cur ^ 1, tix + 1);
            asm volatile("s_waitcnt vmcnt(8)" ::: "memory");
        } else {
            asm volatile("s_waitcnt vmcnt(0)" ::: "memory");
        }
        __builtin_amdgcn_s_barrier();

        const char* Kb = (const char*)lds + cur * 16384;
        const char* Vb = (const char*)lds + 32768 + cur * 16384;

        f32x16 sacc[2];
#pragma unroll
        for (int mb = 0; mb < 2; ++mb)
#pragma unroll
            for (int e = 0; e < 16; ++e) sacc[mb][e] = 0.f;

        __builtin_amdgcn_s_setprio(1);
#pragma unroll
        for (int mb = 0; mb < 2; ++mb) {
            int row = mb * 32 + iln;
            const char* Kr = Kb + row * 256;
            int sw = row & 7;
#pragma unroll
            for (int kk = 0; kk < 8; ++kk) {
                bf16x8 kf = *(const bf16x8*)(Kr + 16 * ((kk * 2 + h) ^ sw));
                sacc[mb] = __builtin_amdgcn_mfma_f32_32x32x16_bf16(kf, qf[kk], sacc[mb], 0, 0, 0);
            }
        }
        __builtin_amdgcn_s_setprio(0);

        const bool domask = (j0 + 63 > qb * 128);
        if (domask) {
#pragma unroll
            for (int mb = 0; mb < 2; ++mb)
#pragma unroll
                for (int reg = 0; reg < 16; ++reg) {
                    int j = j0 + mb * 32 + (reg & 3) + 8 * (reg >> 2) + 4 * h;
                    if (j > i_g) sacc[mb][reg] = -1e30f;
                }
        }

        float red[16];
#pragma unroll
        for (int r = 0; r < 16; ++r) red[r] = fmaxf(sacc[0][r], sacc[1][r]);
#pragma unroll
        for (int s = 8; s >= 1; s >>= 1)
#pragma unroll
            for (int r = 0; r < s; ++r) red[r] = fmaxf(red[r], red[r + s]);
        float mx = fmaxf(red[0], __shfl_xor(red[0], 32, 64));

        if (__any(mx > m_r + 8.f)) {
            float mn = fmaxf(m_r, mx);
            float corr = fexp2(m_r - mn);
            m_r = mn;
            l_r *= corr;
#pragma unroll
            for (int reg = 0; reg < 16; ++reg) {
                int rrow = (reg & 3) + 8 * (reg >> 2) + 4 * h;
                float c = __shfl(corr, rrow, 64);
#pragma unroll
                for (int nb = 0; nb < 4; ++nb) accO[nb][reg] *= c;
            }
        }

        float pe[2][16];
#pragma unroll
        for (int mb = 0; mb < 2; ++mb)
#pragma unroll
            for (int r = 0; r < 16; ++r) pe[mb][r] = fexp2(sacc[mb][r] - m_r);
        float sr[16];
#pragma unroll
        for (int r = 0; r < 16; ++r) sr[r] = pe[0][r] + pe[1][r];
#pragma unroll
        for (int s = 8; s >= 1; s >>= 1)
#pragma unroll
            for (int r = 0; r < s; ++r) sr[r] += sr[r + s];
        l_r += sr[0] + __shfl_xor(sr[0], 32, 64);

        unsigned int pu[2][8];
#pragma unroll
        for (int mb = 0; mb < 2; ++mb)
#pragma unroll
            for (int t = 0; t < 8; ++t)
                pu[mb][t] = cvt_pk_bf16(pe[mb][2 * t], pe[mb][2 * t + 1]);

        unsigned int rv2[2][4];
#pragma unroll
        for (int mb = 0; mb < 2; ++mb)
#pragma unroll
            for (int u = 0; u < 4; ++u) {
                unsigned int sv = h ? pu[mb][(u & 1) + 4 * (u >> 1)]
                                    : pu[mb][2 + (u & 1) + 4 * (u >> 1)];
                rv2[mb][u] = __shfl_xor(sv, 32, 64);
            }

        __builtin_amdgcn_s_setprio(1);
#pragma unroll
        for (int kk2 = 0; kk2 < 4; ++kk2) {
            const int mb = kk2 >> 1, c2 = kk2 & 1;
            unsigned int w0 = h ? rv2[mb][2 * c2 + 0] : pu[mb][4 * c2 + 0];
            unsigned int w1 = h ? rv2[mb][2 * c2 + 1] : pu[mb][4 * c2 + 1];
            unsigned int w2 = h ? pu[mb][4 * c2 + 2] : rv2[mb][2 * c2 + 0];
            unsigned int w3 = h ? pu[mb][4 * c2 + 3] : rv2[mb][2 * c2 + 1];
            uint4 aw; aw.x = w0; aw.y = w1; aw.z = w2; aw.w = w3;
            bf16x8 af = __builtin_bit_cast(bf16x8, aw);
#pragma unroll
            for (int nb = 0; nb < 4; ++nb) {
                int d = nb * 32 + iln;
                int byte = d * 128 + 16 * ((kk2 * 2 + h) ^ (d & 7));
                bf16x8 vf = *(const bf16x8*)(Vb + byte);
                accO[nb] = __builtin_amdgcn_mfma_f32_32x32x16_bf16(af, vf, accO[nb], 0, 0, 0);
            }
        }
        __builtin_amdgcn_s_setprio(0);

        asm volatile("" ::: "memory");
        __builtin_amdgcn_s_barrier();
    }

    const int b = bh >> 4, hh = bh & 15;
    float invl = 1.f / l_r;
#pragma unroll
    for (int reg = 0; reg < 16; ++reg) {
        int rrow = (reg & 3) + 8 * (reg >> 2) + 4 * h;
        float iv = __shfl(invl, rrow, 64);
        int t = qb * 128 + wave * 32 + rrow;
        long base = ((long)(b * Tt + t) * Hh + hh) * Dd;
#pragma unroll
        for (int nb = 0; nb < 4; ++nb)
            o[base + nb * 32 + iln] = f2bf(accO[nb][reg] * iv);
    }
}

// ---------------------------------------------------------------- output projection GEMM
__global__ __launch_bounds__(256) void out_gemm(
    const unsigned short* __restrict__ oIn,
    const unsigned short* __restrict__ woT,
    float* __restrict__ out) {
    __shared__ __align__(16) unsigned short smem[32768];
    const int bm = blockIdx.x, bn = blockIdx.y;
    const int tid = threadIdx.x;
    const int lane = tid & 63;
    const int wave = tid >> 6;
    const int g = lane >> 4;
    const int ln = lane & 15;

    const unsigned short* arow = oIn + (long)bm * 128 * Mm;
    const unsigned short* brow = woT + (long)bn * 128 * Mm;

    f32x4 acc[2][8];
#pragma unroll
    for (int a = 0; a < 2; ++a)
#pragma unroll
        for (int b2 = 0; b2 < 8; ++b2)
#pragma unroll
            for (int e = 0; e < 4; ++e) acc[a][b2][e] = 0.f;

    auto stage = [&](int buf, int kt) {
        const int k0 = kt * 64;
#pragma unroll
        for (int it = 0; it < 4; ++it) {
            int f = it * 256 + tid;
            int r = f >> 3, c = f & 7;
            long off = (long)r * Mm + k0 + ((c ^ (r & 7)) << 3);
            gld16(arow + off, (char*)smem + buf * 32768 + f * 16);
            gld16(brow + off, (char*)smem + buf * 32768 + 16384 + f * 16);
        }
    };

    stage(0, 0);

    for (int kt = 0; kt < Mm / 64; ++kt) {
        const int cur = kt & 1;
        if (kt + 1 < Mm / 64) {
            stage(cur ^ 1, kt + 1);
            asm volatile("s_waitcnt vmcnt(8)" ::: "memory");
        } else {
            asm volatile("s_waitcnt vmcnt(0)" ::: "memory");
        }
        __builtin_amdgcn_s_barrier();

        const char* Ab = (const char*)smem + cur * 32768;
        const char* Bv = Ab + 16384;
#pragma unroll
        for (int kc = 0; kc < 2; ++kc) {
            bf16x8 af[2];
#pragma unroll
            for (int rf = 0; rf < 2; ++rf) {
                int row = wave * 32 + rf * 16 + ln;
                int byte = (row * 128 + kc * 64 + g * 16) ^ ((row & 7) << 4);
                af[rf] = *(const bf16x8*)(Ab + byte);
            }
#pragma unroll
            for (int ni = 0; ni < 8; ++ni) {
                int row = ni * 16 + ln;
                int byte = (row * 128 + kc * 64 + g * 16) ^ ((row & 7) << 4);
                bf16x8 bfv = *(const bf16x8*)(Bv + byte);
#pragma unroll
                for (int rf = 0; rf < 2; ++rf)
                    acc[rf][ni] = __builtin_amdgcn_mfma_f32_16x16x32_bf16(af[rf], bfv, acc[rf][ni], 0, 0, 0);
            }
        }
        asm volatile("" ::: "memory");
        __builtin_amdgcn_s_barrier();
    }

#pragma unroll
    for (int rf = 0; rf < 2; ++rf)
#pragma unroll
        for (int reg = 0; reg < 4; ++reg) {
            long row = bm * 128 + wave * 32 + rf * 16 + g * 4 + reg;
#pragma unroll
            for (int ni = 0; ni < 8; ++ni)
                out[row * Mm + bn * 128 + ni * 16 + ln] = acc[rf][ni][reg];
        }
}

// ---------------------------------------------------------------- launch

extern "C" void kernel_launch(void* const* d_in, const int* in_sizes, int n_in,
                              void* d_out, int out_size, void* d_ws, size_t ws_size,
                              hipStream_t stream) {
    const float* x    = (const float*)d_in[0];
    const float* w_aq = (const float*)d_in[1];
    const float* w_ak = (const float*)d_in[2];
    const float* w_av = (const float*)d_in[3];
    const float* w_ao = (const float*)d_in[4];
    float* out = (float*)d_out;

    char* ws = (char*)d_ws;
    const long SZ_BTM = 16777216;   // B*T*M * 2B
    const long SZ_W   = 8388608;    // 2048*2048 * 2B
    unsigned short* xb  = (unsigned short*)(ws);
    unsigned short* qB  = (unsigned short*)(ws + SZ_BTM);
    unsigned short* kB  = (unsigned short*)(ws + 2 * SZ_BTM);
    unsigned short* vtB = (unsigned short*)(ws + 3 * SZ_BTM);
    unsigned short* oB  = (unsigned short*)(ws + 4 * SZ_BTM);
    unsigned short* wqT = (unsigned short*)(ws + 5 * SZ_BTM);
    unsigned short* wkT = (unsigned short*)(ws + 5 * SZ_BTM + SZ_W);
    unsigned short* wvT = (unsigned short*)(ws + 5 * SZ_BTM + 2 * SZ_W);
    unsigned short* woT = (unsigned short*)(ws + 5 * SZ_BTM + 3 * SZ_W);
    float* cosT = (float*)(ws + 5 * SZ_BTM + 4 * SZ_W);
    float* sinT = (float*)(ws + 5 * SZ_BTM + 4 * SZ_W + 524288);

    cvt_x_kernel<<<8192, 256, 0, stream>>>(x, xb);
    transpose_cvt_qkv<<<dim3(64, 4, 48), 256, 0, stream>>>(w_aq, w_ak, w_av, wqT);
    transpose_cvt<<<dim3(64, 64, 1), 256, 0, stream>>>(w_ao, woT, 2048, 2048, 0, 0);
    rope_tab<<<512, 256, 0, stream>>>(cosT, sinT);

    proj_gemm2<<<dim3(16, 16), 512, 0, stream>>>(xb, wqT, wkT, wvT, qB, kB, vtB, cosT, sinT);
    attn_kernel<<<dim3(512), 256, 0, stream>>>(qB, kB, vtB, oB);
    out_gemm<<<dim3(32, 16), 256, 0, stream>>>(oB, woT, out);
}